// Round 1
// baseline (1413.561 us; speedup 1.0000x reference)
//
#include <hip/hip_runtime.h>
#include <math.h>

#define NODES 50000
#define NEDGE 800000
#define ETOT  (NEDGE + NODES)   // edges + self loops = 850000
#define NF    256
#define F1    128               // HEADS*NHID
#define NHEAD 8
#define NHID  16
#define NC    40

// ---------- helpers ----------
__device__ __forceinline__ unsigned ordKey(float f) {
    unsigned b = __float_as_uint(f);
    return (b & 0x80000000u) ? ~b : (b | 0x80000000u);
}
__device__ __forceinline__ float decKey(unsigned k) {
    unsigned b = (k & 0x80000000u) ? (k ^ 0x80000000u) : ~k;
    return __uint_as_float(b);
}
__device__ __forceinline__ float lrelu(float v) { return v > 0.f ? v : 0.2f * v; }

// ---------- edge index dtype detect + normalize ----------
__global__ void detect_k(const unsigned* __restrict__ u, unsigned* __restrict__ flag) {
    int t = threadIdx.x;              // 256 threads
    if (u[2 * t + 1] != 0u) atomicOr(flag, 1u);   // nonzero hi-word pattern => int32 data
}
__global__ void convert_k(const unsigned* __restrict__ u, int* __restrict__ srcE,
                          int* __restrict__ dstE, const unsigned* __restrict__ flag) {
    int e = blockIdx.x * 256 + threadIdx.x;
    if (e >= NEDGE) return;
    if (*flag) {  // int32 layout [2][E]
        srcE[e] = (int)u[e];
        dstE[e] = (int)u[NEDGE + e];
    } else {      // int64 layout [2][E], take lo words
        srcE[e] = (int)u[2 * e];
        dstE[e] = (int)u[2 * NEDGE + 2 * e];
    }
}

// ---------- GEMM1: x[N,256] @ W1[256,128] -> h1[N,128] ----------
__global__ __launch_bounds__(256) void gemm1(const float* __restrict__ x,
                                             const float* __restrict__ W,
                                             float* __restrict__ h1) {
    __shared__ float xs[32][NF];  // 32 KB
    int t = threadIdx.x;
    int base = blockIdx.x * 32;
    // stage 32 rows x 256 floats = 2048 float4; 8 per thread
#pragma unroll
    for (int r = 0; r < 8; ++r) {
        int idx = r * 256 + t;       // float4 index
        int row = idx >> 6;          // 64 float4 per row
        int c4 = idx & 63;
        int n = base + row;
        float4 v = make_float4(0.f, 0.f, 0.f, 0.f);
        if (n < NODES) v = ((const float4*)(x + (size_t)n * NF))[c4];
        ((float4*)(&xs[row][0]))[c4] = v;
    }
    __syncthreads();
    int tc = t & 31;   // column group: cols c0..c0+3
    int ng = t >> 5;   // node group 0..7 (4 nodes each)
    int c0 = tc * 4;
    float acc[4][4];
#pragma unroll
    for (int j = 0; j < 4; ++j)
#pragma unroll
        for (int i = 0; i < 4; ++i) acc[j][i] = 0.f;

    for (int k4 = 0; k4 < NF / 4; ++k4) {
        float4 xv[4];
#pragma unroll
        for (int j = 0; j < 4; ++j)
            xv[j] = *(const float4*)(&xs[ng * 4 + j][k4 * 4]);
        const float* wp = W + (size_t)k4 * 4 * F1 + c0;
#pragma unroll
        for (int dk = 0; dk < 4; ++dk) {
            float4 wv = *(const float4*)(wp + dk * F1);
            float xk[4] = {0.f, 0.f, 0.f, 0.f};
#pragma unroll
            for (int j = 0; j < 4; ++j) {
                float xj = (dk == 0) ? xv[j].x : (dk == 1) ? xv[j].y : (dk == 2) ? xv[j].z : xv[j].w;
                xk[j] = xj;
            }
#pragma unroll
            for (int j = 0; j < 4; ++j) {
                acc[j][0] += xk[j] * wv.x;
                acc[j][1] += xk[j] * wv.y;
                acc[j][2] += xk[j] * wv.z;
                acc[j][3] += xk[j] * wv.w;
            }
        }
    }
#pragma unroll
    for (int j = 0; j < 4; ++j) {
        int n = base + ng * 4 + j;
        if (n < NODES) {
            float4 o = make_float4(acc[j][0], acc[j][1], acc[j][2], acc[j][3]);
            *(float4*)(h1 + (size_t)n * F1 + c0) = o;
        }
    }
}

// ---------- a_src1/a_dst1: [N,8] ----------
__global__ void a1k(const float* __restrict__ h1, const float* __restrict__ att_s,
                    const float* __restrict__ att_d, float* __restrict__ as,
                    float* __restrict__ ad) {
    int t = blockIdx.x * 256 + threadIdx.x;
    if (t >= NODES * NHEAD) return;
    int n = t >> 3, h = t & 7;
    const float4* p = (const float4*)(h1 + (size_t)n * F1 + h * NHID);
    const float4* ws = (const float4*)(att_s + h * NHID);
    const float4* wd = (const float4*)(att_d + h * NHID);
    float ss = 0.f, dd = 0.f;
#pragma unroll
    for (int i = 0; i < 4; ++i) {
        float4 hv = p[i], sv = ws[i], dv = wd[i];
        ss += hv.x * sv.x + hv.y * sv.y + hv.z * sv.z + hv.w * sv.w;
        dd += hv.x * dv.x + hv.y * dv.y + hv.z * dv.z + hv.w * dv.w;
    }
    as[t] = ss;
    ad[t] = dd;
}

// ---------- L1 edge pass 1: segment max ----------
__global__ __launch_bounds__(256) void edge_max1(const int* __restrict__ srcE,
                                                 const int* __restrict__ dstE,
                                                 const float* __restrict__ as,
                                                 const float* __restrict__ ad,
                                                 unsigned* __restrict__ m1u) {
    int e = blockIdx.x * 256 + threadIdx.x;
    if (e >= ETOT) return;
    int s, d;
    if (e < NEDGE) { s = srcE[e]; d = dstE[e]; } else { s = d = e - NEDGE; }
    float4 s0 = *(const float4*)(as + (size_t)s * 8);
    float4 s1 = *(const float4*)(as + (size_t)s * 8 + 4);
    float4 t0 = *(const float4*)(ad + (size_t)d * 8);
    float4 t1 = *(const float4*)(ad + (size_t)d * 8 + 4);
    float l[8] = {s0.x + t0.x, s0.y + t0.y, s0.z + t0.z, s0.w + t0.w,
                  s1.x + t1.x, s1.y + t1.y, s1.z + t1.z, s1.w + t1.w};
    unsigned* mp = m1u + (size_t)d * 8;
#pragma unroll
    for (int h = 0; h < 8; ++h) atomicMax(mp + h, ordKey(lrelu(l[h])));
}

// ---------- L1 edge pass 2: denom ----------
__global__ __launch_bounds__(256) void edge_den1(const int* __restrict__ srcE,
                                                 const int* __restrict__ dstE,
                                                 const float* __restrict__ as,
                                                 const float* __restrict__ ad,
                                                 const unsigned* __restrict__ m1u,
                                                 float* __restrict__ den) {
    int e = blockIdx.x * 256 + threadIdx.x;
    if (e >= ETOT) return;
    int s, d;
    if (e < NEDGE) { s = srcE[e]; d = dstE[e]; } else { s = d = e - NEDGE; }
    float4 s0 = *(const float4*)(as + (size_t)s * 8);
    float4 s1 = *(const float4*)(as + (size_t)s * 8 + 4);
    float4 t0 = *(const float4*)(ad + (size_t)d * 8);
    float4 t1 = *(const float4*)(ad + (size_t)d * 8 + 4);
    float l[8] = {s0.x + t0.x, s0.y + t0.y, s0.z + t0.z, s0.w + t0.w,
                  s1.x + t1.x, s1.y + t1.y, s1.z + t1.z, s1.w + t1.w};
    uint4 m0 = *(const uint4*)(m1u + (size_t)d * 8);
    uint4 m1 = *(const uint4*)(m1u + (size_t)d * 8 + 4);
    float m[8] = {decKey(m0.x), decKey(m0.y), decKey(m0.z), decKey(m0.w),
                  decKey(m1.x), decKey(m1.y), decKey(m1.z), decKey(m1.w)};
    float* dp = den + (size_t)d * 8;
#pragma unroll
    for (int h = 0; h < 8; ++h) atomicAdd(dp + h, expf(lrelu(l[h]) - m[h]));
}

// ---------- L1 edge pass 3: alpha * h1[src] -> atomicAdd out1[dst] ----------
__global__ __launch_bounds__(256) void edge_msg1(const int* __restrict__ srcE,
                                                 const int* __restrict__ dstE,
                                                 const float* __restrict__ as,
                                                 const float* __restrict__ ad,
                                                 const unsigned* __restrict__ m1u,
                                                 const float* __restrict__ den,
                                                 const float* __restrict__ h1,
                                                 float* __restrict__ out1) {
    int t = threadIdx.x;
    long long gid = (long long)blockIdx.x * 256 + t;
    int e = (int)(gid >> 7);   // 128 threads per edge
    int c = t & 127;
    if (e >= ETOT) return;
    int s, dn;
    if (e < NEDGE) { s = srcE[e]; dn = dstE[e]; } else { s = dn = e - NEDGE; }
    int h = c >> 4;
    float alpha = 0.f;
    if ((c & 15) == 0) {  // leader per (edge, head)
        float l = as[(size_t)s * 8 + h] + ad[(size_t)dn * 8 + h];
        l = lrelu(l);
        float m = decKey(m1u[(size_t)dn * 8 + h]);
        float dd = den[(size_t)dn * 8 + h];
        alpha = expf(l - m) / (dd + 1e-16f);
    }
    int lane = t & 63;
    alpha = __shfl(alpha, (lane & ~15), 64);
    float msg = h1[(size_t)s * F1 + c] * alpha;
    atomicAdd(&out1[(size_t)dn * F1 + c], msg);
}

// ---------- bias + ELU in place ----------
__global__ void eluk(float* __restrict__ y, const float* __restrict__ b1) {
    int i = blockIdx.x * 256 + threadIdx.x;
    if (i >= NODES * F1) return;
    float v = y[i] + b1[i & 127];
    y[i] = v > 0.f ? v : expm1f(v);
}

// ---------- GEMM2: y[N,128] @ W2[128,40] -> h2[N,40] ----------
__global__ __launch_bounds__(320) void gemm2(const float* __restrict__ a,
                                             const float* __restrict__ W,
                                             float* __restrict__ h2) {
    __shared__ float xs[8][132];
    int t = threadIdx.x;
    int base = blockIdx.x * 8;
    if (t < 256) {
        int row = t >> 5, c4 = t & 31;
        int n = base + row;
        float4 v = make_float4(0.f, 0.f, 0.f, 0.f);
        if (n < NODES) v = ((const float4*)(a + (size_t)n * F1))[c4];
        *(float4*)(&xs[row][c4 * 4]) = v;
    }
    __syncthreads();
    int n = t / 40, c = t % 40;
    float acc = 0.f;
    for (int k4 = 0; k4 < 32; ++k4) {
        float4 xv = *(const float4*)(&xs[n][k4 * 4]);
        const float* wp = W + (size_t)k4 * 4 * NC + c;
        acc += xv.x * wp[0];
        acc += xv.y * wp[NC];
        acc += xv.z * wp[2 * NC];
        acc += xv.w * wp[3 * NC];
    }
    int node = base + n;
    if (node < NODES) h2[(size_t)node * NC + c] = acc;
}

// ---------- a_src2/a_dst2: [N] ----------
__global__ void a2k(const float* __restrict__ h2, const float* __restrict__ att_s,
                    const float* __restrict__ att_d, float* __restrict__ as,
                    float* __restrict__ ad) {
    int n = blockIdx.x * 256 + threadIdx.x;
    if (n >= NODES) return;
    const float4* p = (const float4*)(h2 + (size_t)n * NC);
    float ss = 0.f, dd = 0.f;
#pragma unroll
    for (int i = 0; i < 10; ++i) {
        float4 hv = p[i];
        float4 sv = ((const float4*)att_s)[i];
        float4 dv = ((const float4*)att_d)[i];
        ss += hv.x * sv.x + hv.y * sv.y + hv.z * sv.z + hv.w * sv.w;
        dd += hv.x * dv.x + hv.y * dv.y + hv.z * dv.z + hv.w * dv.w;
    }
    as[n] = ss;
    ad[n] = dd;
}

// ---------- L2 edge passes (H=1) ----------
__global__ void edge_max2(const int* __restrict__ srcE, const int* __restrict__ dstE,
                          const float* __restrict__ as, const float* __restrict__ ad,
                          unsigned* __restrict__ m2u) {
    int e = blockIdx.x * 256 + threadIdx.x;
    if (e >= ETOT) return;
    int s, d;
    if (e < NEDGE) { s = srcE[e]; d = dstE[e]; } else { s = d = e - NEDGE; }
    float l = lrelu(as[s] + ad[d]);
    atomicMax(m2u + d, ordKey(l));
}
__global__ void edge_den2(const int* __restrict__ srcE, const int* __restrict__ dstE,
                          const float* __restrict__ as, const float* __restrict__ ad,
                          const unsigned* __restrict__ m2u, float* __restrict__ den) {
    int e = blockIdx.x * 256 + threadIdx.x;
    if (e >= ETOT) return;
    int s, d;
    if (e < NEDGE) { s = srcE[e]; d = dstE[e]; } else { s = d = e - NEDGE; }
    float l = lrelu(as[s] + ad[d]);
    atomicAdd(den + d, expf(l - decKey(m2u[d])));
}
__global__ void alpha2k(const int* __restrict__ srcE, const int* __restrict__ dstE,
                        const float* __restrict__ as, const float* __restrict__ ad,
                        const unsigned* __restrict__ m2u, const float* __restrict__ den,
                        float* __restrict__ alpha2) {
    int e = blockIdx.x * 256 + threadIdx.x;
    if (e >= ETOT) return;
    int s, d;
    if (e < NEDGE) { s = srcE[e]; d = dstE[e]; } else { s = d = e - NEDGE; }
    float l = lrelu(as[s] + ad[d]);
    alpha2[e] = expf(l - decKey(m2u[d])) / (den[d] + 1e-16f);
}
__global__ __launch_bounds__(320) void edge_msg2(const int* __restrict__ srcE,
                                                 const int* __restrict__ dstE,
                                                 const float* __restrict__ alpha2,
                                                 const float* __restrict__ h2,
                                                 float* __restrict__ out) {
    int t = threadIdx.x;
    int e = blockIdx.x * 8 + t / 40;
    int c = t % 40;
    if (e >= ETOT) return;
    int s, d;
    if (e < NEDGE) { s = srcE[e]; d = dstE[e]; } else { s = d = e - NEDGE; }
    float msg = h2[(size_t)s * NC + c] * alpha2[e];
    atomicAdd(&out[(size_t)d * NC + c], msg);
}

// ---------- bias + log_softmax in place ----------
__global__ void lsmk(float* __restrict__ out, const float* __restrict__ b2) {
    int n = blockIdx.x * 256 + threadIdx.x;
    if (n >= NODES) return;
    float v[NC];
    float m = -1e30f;
#pragma unroll
    for (int c = 0; c < NC; ++c) {
        v[c] = out[(size_t)n * NC + c] + b2[c];
        m = fmaxf(m, v[c]);
    }
    float ssum = 0.f;
#pragma unroll
    for (int c = 0; c < NC; ++c) ssum += expf(v[c] - m);
    float lse = m + logf(ssum);
#pragma unroll
    for (int c = 0; c < NC; ++c) out[(size_t)n * NC + c] = v[c] - lse;
}

extern "C" void kernel_launch(void* const* d_in, const int* in_sizes, int n_in,
                              void* d_out, int out_size, void* d_ws, size_t ws_size,
                              hipStream_t stream) {
    const float* x       = (const float*)d_in[0];
    const unsigned* eidx = (const unsigned*)d_in[1];
    const float* W1      = (const float*)d_in[2];
    const float* atts1   = (const float*)d_in[3];
    const float* attd1   = (const float*)d_in[4];
    const float* b1      = (const float*)d_in[5];
    const float* W2      = (const float*)d_in[6];
    const float* atts2   = (const float*)d_in[7];
    const float* attd2   = (const float*)d_in[8];
    const float* b2      = (const float*)d_in[9];
    float* out = (float*)d_out;

    char* base = (char*)d_ws;
    size_t off = 0;
    auto take = [&](size_t elems) {
        void* p = base + off;
        off = (off + elems * 4 + 255) & ~(size_t)255;
        return p;
    };
    unsigned* flag = (unsigned*)take(64);
    int* srcE      = (int*)take(NEDGE);
    int* dstE      = (int*)take(NEDGE);
    char* l2base = base + off;  // overlay region (h1 is dead by layer 2)
    float* h1      = (float*)take((size_t)NODES * F1);
    float* as1     = (float*)take((size_t)NODES * 8);
    float* ad1     = (float*)take((size_t)NODES * 8);
    unsigned* m1u  = (unsigned*)take((size_t)NODES * 8);
    float* den1    = (float*)take((size_t)NODES * 8);
    float* out1    = (float*)take((size_t)NODES * F1);

    size_t o2 = 0;
    auto take2 = [&](size_t elems) {
        void* p = l2base + o2;
        o2 = (o2 + elems * 4 + 255) & ~(size_t)255;
        return p;
    };
    float* h2      = (float*)take2((size_t)NODES * NC);
    float* as2     = (float*)take2(NODES);
    float* ad2     = (float*)take2(NODES);
    unsigned* m2u  = (unsigned*)take2(NODES);
    float* den2    = (float*)take2(NODES);
    float* alpha2  = (float*)take2(ETOT);

    // zero accumulators (layer-1 + output); layer-2 accumulators are zeroed
    // later because they overlay h1.
    hipMemsetAsync(flag, 0, 4, stream);
    hipMemsetAsync(m1u, 0, (size_t)NODES * 8 * 4, stream);
    hipMemsetAsync(den1, 0, (size_t)NODES * 8 * 4, stream);
    hipMemsetAsync(out1, 0, (size_t)NODES * F1 * 4, stream);
    hipMemsetAsync(d_out, 0, (size_t)out_size * 4, stream);

    detect_k<<<1, 256, 0, stream>>>(eidx, flag);
    convert_k<<<(NEDGE + 255) / 256, 256, 0, stream>>>(eidx, srcE, dstE, flag);

    gemm1<<<(NODES + 31) / 32, 256, 0, stream>>>(x, W1, h1);
    a1k<<<(NODES * NHEAD + 255) / 256, 256, 0, stream>>>(h1, atts1, attd1, as1, ad1);
    edge_max1<<<(ETOT + 255) / 256, 256, 0, stream>>>(srcE, dstE, as1, ad1, m1u);
    edge_den1<<<(ETOT + 255) / 256, 256, 0, stream>>>(srcE, dstE, as1, ad1, m1u, den1);
    edge_msg1<<<ETOT / 2, 256, 0, stream>>>(srcE, dstE, as1, ad1, m1u, den1, h1, out1);
    eluk<<<(NODES * F1 + 255) / 256, 256, 0, stream>>>(out1, b1);

    // layer-2 accumulators live in the (now dead) h1 region
    hipMemsetAsync(m2u, 0, (size_t)NODES * 4, stream);
    hipMemsetAsync(den2, 0, (size_t)NODES * 4, stream);

    gemm2<<<(NODES + 7) / 8, 320, 0, stream>>>(out1, W2, h2);
    a2k<<<(NODES + 255) / 256, 256, 0, stream>>>(h2, atts2, attd2, as2, ad2);
    edge_max2<<<(ETOT + 255) / 256, 256, 0, stream>>>(srcE, dstE, as2, ad2, m2u);
    edge_den2<<<(ETOT + 255) / 256, 256, 0, stream>>>(srcE, dstE, as2, ad2, m2u, den2);
    alpha2k<<<(ETOT + 255) / 256, 256, 0, stream>>>(srcE, dstE, as2, ad2, m2u, den2, alpha2);
    edge_msg2<<<(ETOT + 7) / 8, 320, 0, stream>>>(srcE, dstE, alpha2, h2, out);
    lsmk<<<(NODES + 255) / 256, 256, 0, stream>>>(out, b2);
}

// Round 2
// 626.639 us; speedup vs baseline: 2.2558x; 2.2558x over previous
//
#include <hip/hip_runtime.h>
#include <math.h>

#define NODES 50000
#define NEDGE 800000
#define ETOT  (NEDGE + NODES)   // edges + self loops = 850000
#define NF    256
#define F1    128               // HEADS*NHID
#define NHEAD 8
#define NHID  16
#define NC    40

__device__ __forceinline__ float lrelu(float v) { return v > 0.f ? v : 0.2f * v; }

// ---------- edge index dtype detect + normalize ----------
__global__ void detect_k(const unsigned* __restrict__ u, unsigned* __restrict__ flag) {
    int t = threadIdx.x;              // 256 threads
    if (u[2 * t + 1] != 0u) atomicOr(flag, 1u);   // nonzero hi-word pattern => int32 data
}
__global__ void convert_k(const unsigned* __restrict__ u, int* __restrict__ srcE,
                          int* __restrict__ dstE, const unsigned* __restrict__ flag) {
    int e = blockIdx.x * 256 + threadIdx.x;
    if (e >= NEDGE) return;
    if (*flag) {  // int32 layout [2][E]
        srcE[e] = (int)u[e];
        dstE[e] = (int)u[NEDGE + e];
    } else {      // int64 layout [2][E], take lo words
        srcE[e] = (int)u[2 * e];
        dstE[e] = (int)u[2 * NEDGE + 2 * e];
    }
}

// ---------- CSR build ----------
__global__ void hist_k(const int* __restrict__ dstE, int* __restrict__ cnt) {
    int e = blockIdx.x * 256 + threadIdx.x;
    if (e >= ETOT) return;
    int d = (e < NEDGE) ? dstE[e] : e - NEDGE;
    atomicAdd(&cnt[d], 1);
}

__global__ __launch_bounds__(1024) void scan_k(const int* __restrict__ cnt,
                                               int* __restrict__ rowPtr) {
    __shared__ int part[1024];
    const int CH = 49;   // 1024*49 = 50176 >= NODES
    int t = threadIdx.x;
    int beg = t * CH;
    int sum = 0;
    for (int i = 0; i < CH; ++i) {
        int idx = beg + i;
        sum += (idx < NODES) ? cnt[idx] : 0;
    }
    part[t] = sum;
    __syncthreads();
    // inclusive Hillis-Steele scan
    for (int off = 1; off < 1024; off <<= 1) {
        int v = (t >= off) ? part[t - off] : 0;
        __syncthreads();
        part[t] += v;
        __syncthreads();
    }
    int excl = part[t] - sum;   // exclusive prefix for this thread's chunk
    int running = excl;
    for (int i = 0; i < CH; ++i) {
        int idx = beg + i;
        if (idx < NODES) {
            rowPtr[idx] = running;
            running += cnt[idx];
        }
    }
    if (t == 1023) rowPtr[NODES] = part[1023];
}

__global__ void scatter_k(const int* __restrict__ srcE, const int* __restrict__ dstE,
                          const int* __restrict__ rowPtr, int* __restrict__ fill,
                          int* __restrict__ csrSrc) {
    int e = blockIdx.x * 256 + threadIdx.x;
    if (e >= ETOT) return;
    int s, d;
    if (e < NEDGE) { s = srcE[e]; d = dstE[e]; } else { s = d = e - NEDGE; }
    int pos = rowPtr[d] + atomicAdd(&fill[d], 1);
    csrSrc[pos] = s;
}

// ---------- GEMM1: x[N,256] @ W1[256,128] -> h1[N,128] ----------
__global__ __launch_bounds__(256) void gemm1(const float* __restrict__ x,
                                             const float* __restrict__ W,
                                             float* __restrict__ h1) {
    __shared__ float xs[32][NF];  // 32 KB
    int t = threadIdx.x;
    int base = blockIdx.x * 32;
#pragma unroll
    for (int r = 0; r < 8; ++r) {
        int idx = r * 256 + t;       // float4 index
        int row = idx >> 6;          // 64 float4 per row
        int c4 = idx & 63;
        int n = base + row;
        float4 v = make_float4(0.f, 0.f, 0.f, 0.f);
        if (n < NODES) v = ((const float4*)(x + (size_t)n * NF))[c4];
        ((float4*)(&xs[row][0]))[c4] = v;
    }
    __syncthreads();
    int tc = t & 31;   // column group: cols c0..c0+3
    int ng = t >> 5;   // node group 0..7 (4 nodes each)
    int c0 = tc * 4;
    float acc[4][4];
#pragma unroll
    for (int j = 0; j < 4; ++j)
#pragma unroll
        for (int i = 0; i < 4; ++i) acc[j][i] = 0.f;

    for (int k4 = 0; k4 < NF / 4; ++k4) {
        float4 xv[4];
#pragma unroll
        for (int j = 0; j < 4; ++j)
            xv[j] = *(const float4*)(&xs[ng * 4 + j][k4 * 4]);
        const float* wp = W + (size_t)k4 * 4 * F1 + c0;
#pragma unroll
        for (int dk = 0; dk < 4; ++dk) {
            float4 wv = *(const float4*)(wp + dk * F1);
#pragma unroll
            for (int j = 0; j < 4; ++j) {
                float xj = (dk == 0) ? xv[j].x : (dk == 1) ? xv[j].y : (dk == 2) ? xv[j].z : xv[j].w;
                acc[j][0] += xj * wv.x;
                acc[j][1] += xj * wv.y;
                acc[j][2] += xj * wv.z;
                acc[j][3] += xj * wv.w;
            }
        }
    }
#pragma unroll
    for (int j = 0; j < 4; ++j) {
        int n = base + ng * 4 + j;
        if (n < NODES) {
            float4 o = make_float4(acc[j][0], acc[j][1], acc[j][2], acc[j][3]);
            *(float4*)(h1 + (size_t)n * F1 + c0) = o;
        }
    }
}

// ---------- a_src1/a_dst1: [N,8] ----------
__global__ void a1k(const float* __restrict__ h1, const float* __restrict__ att_s,
                    const float* __restrict__ att_d, float* __restrict__ as,
                    float* __restrict__ ad) {
    int t = blockIdx.x * 256 + threadIdx.x;
    if (t >= NODES * NHEAD) return;
    int n = t >> 3, h = t & 7;
    const float4* p = (const float4*)(h1 + (size_t)n * F1 + h * NHID);
    const float4* ws = (const float4*)(att_s + h * NHID);
    const float4* wd = (const float4*)(att_d + h * NHID);
    float ss = 0.f, dd = 0.f;
#pragma unroll
    for (int i = 0; i < 4; ++i) {
        float4 hv = p[i], sv = ws[i], dv = wd[i];
        ss += hv.x * sv.x + hv.y * sv.y + hv.z * sv.z + hv.w * sv.w;
        dd += hv.x * dv.x + hv.y * dv.y + hv.z * dv.z + hv.w * dv.w;
    }
    as[t] = ss;
    ad[t] = dd;
}

// ---------- L1 attention: per (dst, head) max + denom ----------
__global__ void attn1(const int* __restrict__ rowPtr, const int* __restrict__ csrSrc,
                      const float* __restrict__ as, const float* __restrict__ ad,
                      float* __restrict__ m1, float* __restrict__ den1) {
    int g = blockIdx.x * 256 + threadIdx.x;
    if (g >= NODES * NHEAD) return;
    int d = g >> 3, h = g & 7;
    float adv = ad[g];
    int rs = rowPtr[d], re = rowPtr[d + 1];
    float m = -1e30f;
    for (int j = rs; j < re; ++j)
        m = fmaxf(m, lrelu(as[(size_t)csrSrc[j] * NHEAD + h] + adv));
    float ssum = 0.f;
    for (int j = rs; j < re; ++j)
        ssum += expf(lrelu(as[(size_t)csrSrc[j] * NHEAD + h] + adv) - m);
    m1[g] = m;
    den1[g] = ssum;
}

// ---------- L1 message gather: block(128) per dst, fused bias+ELU ----------
__global__ __launch_bounds__(128) void msg1(const int* __restrict__ rowPtr,
                                            const int* __restrict__ csrSrc,
                                            const float* __restrict__ as,
                                            const float* __restrict__ ad,
                                            const float* __restrict__ m1,
                                            const float* __restrict__ den1,
                                            const float* __restrict__ h1,
                                            const float* __restrict__ b1,
                                            float* __restrict__ out1) {
    int d = blockIdx.x;
    int t = threadIdx.x;          // channel 0..127
    int h = t >> 4;               // head
    int lane = t & 63;
    bool leader = (t & 15) == 0;
    float adv = 0.f, mv = 0.f, inv = 0.f;
    if (leader) {
        adv = ad[(size_t)d * NHEAD + h];
        mv  = m1[(size_t)d * NHEAD + h];
        inv = 1.f / (den1[(size_t)d * NHEAD + h] + 1e-16f);
    }
    int rs = rowPtr[d], re = rowPtr[d + 1];
    float acc = 0.f;
    for (int j = rs; j < re; ++j) {
        int s = csrSrc[j];
        float alpha = 0.f;
        if (leader)
            alpha = expf(lrelu(as[(size_t)s * NHEAD + h] + adv) - mv) * inv;
        alpha = __shfl(alpha, lane & ~15, 64);
        acc += alpha * h1[(size_t)s * F1 + t];
    }
    float v = acc + b1[t];
    out1[(size_t)d * F1 + t] = v > 0.f ? v : expm1f(v);
}

// ---------- GEMM2: y[N,128] @ W2[128,40] -> h2[N,40] ----------
__global__ __launch_bounds__(320) void gemm2(const float* __restrict__ a,
                                             const float* __restrict__ W,
                                             float* __restrict__ h2) {
    __shared__ float xs[8][132];
    int t = threadIdx.x;
    int base = blockIdx.x * 8;
    if (t < 256) {
        int row = t >> 5, c4 = t & 31;
        int n = base + row;
        float4 v = make_float4(0.f, 0.f, 0.f, 0.f);
        if (n < NODES) v = ((const float4*)(a + (size_t)n * F1))[c4];
        *(float4*)(&xs[row][c4 * 4]) = v;
    }
    __syncthreads();
    int n = t / 40, c = t % 40;
    float acc = 0.f;
    for (int k4 = 0; k4 < 32; ++k4) {
        float4 xv = *(const float4*)(&xs[n][k4 * 4]);
        const float* wp = W + (size_t)k4 * 4 * NC + c;
        acc += xv.x * wp[0];
        acc += xv.y * wp[NC];
        acc += xv.z * wp[2 * NC];
        acc += xv.w * wp[3 * NC];
    }
    int node = base + n;
    if (node < NODES) h2[(size_t)node * NC + c] = acc;
}

// ---------- a_src2/a_dst2: [N] ----------
__global__ void a2k(const float* __restrict__ h2, const float* __restrict__ att_s,
                    const float* __restrict__ att_d, float* __restrict__ as,
                    float* __restrict__ ad) {
    int n = blockIdx.x * 256 + threadIdx.x;
    if (n >= NODES) return;
    const float4* p = (const float4*)(h2 + (size_t)n * NC);
    float ss = 0.f, dd = 0.f;
#pragma unroll
    for (int i = 0; i < 10; ++i) {
        float4 hv = p[i];
        float4 sv = ((const float4*)att_s)[i];
        float4 dv = ((const float4*)att_d)[i];
        ss += hv.x * sv.x + hv.y * sv.y + hv.z * sv.z + hv.w * sv.w;
        dd += hv.x * dv.x + hv.y * dv.y + hv.z * dv.z + hv.w * dv.w;
    }
    as[n] = ss;
    ad[n] = dd;
}

// ---------- L2 attention: per dst max + denom ----------
__global__ void attn2(const int* __restrict__ rowPtr, const int* __restrict__ csrSrc,
                      const float* __restrict__ as, const float* __restrict__ ad,
                      float* __restrict__ m2, float* __restrict__ den2) {
    int d = blockIdx.x * 256 + threadIdx.x;
    if (d >= NODES) return;
    float adv = ad[d];
    int rs = rowPtr[d], re = rowPtr[d + 1];
    float m = -1e30f;
    for (int j = rs; j < re; ++j)
        m = fmaxf(m, lrelu(as[csrSrc[j]] + adv));
    float ssum = 0.f;
    for (int j = rs; j < re; ++j)
        ssum += expf(lrelu(as[csrSrc[j]] + adv) - m);
    m2[d] = m;
    den2[d] = ssum;
}

// ---------- L2 message gather: wave per dst, fused bias + log_softmax ----------
__global__ __launch_bounds__(256) void msg2(const int* __restrict__ rowPtr,
                                            const int* __restrict__ csrSrc,
                                            const float* __restrict__ as,
                                            const float* __restrict__ ad,
                                            const float* __restrict__ m2,
                                            const float* __restrict__ den2,
                                            const float* __restrict__ h2,
                                            const float* __restrict__ b2,
                                            float* __restrict__ out) {
    int wid = threadIdx.x >> 6;
    int d = blockIdx.x * 4 + wid;
    int lane = threadIdx.x & 63;
    if (d >= NODES) return;
    float adv = ad[d], mv = m2[d];
    float inv = 1.f / (den2[d] + 1e-16f);
    int rs = rowPtr[d], re = rowPtr[d + 1];
    float acc = 0.f;
    for (int j = rs; j < re; ++j) {
        int s = csrSrc[j];
        float alpha = 0.f;
        if (lane == 0)
            alpha = expf(lrelu(as[s] + adv) - mv) * inv;
        alpha = __shfl(alpha, 0, 64);
        if (lane < NC) acc += alpha * h2[(size_t)s * NC + lane];
    }
    float v = (lane < NC) ? acc + b2[lane] : -1e30f;
    float mm = v;
#pragma unroll
    for (int off = 32; off; off >>= 1) mm = fmaxf(mm, __shfl_xor(mm, off, 64));
    float e = (lane < NC) ? expf(v - mm) : 0.f;
    float ssum = e;
#pragma unroll
    for (int off = 32; off; off >>= 1) ssum += __shfl_xor(ssum, off, 64);
    float lse = mm + logf(ssum);
    if (lane < NC) out[(size_t)d * NC + lane] = v - lse;
}

extern "C" void kernel_launch(void* const* d_in, const int* in_sizes, int n_in,
                              void* d_out, int out_size, void* d_ws, size_t ws_size,
                              hipStream_t stream) {
    const float* x       = (const float*)d_in[0];
    const unsigned* eidx = (const unsigned*)d_in[1];
    const float* W1      = (const float*)d_in[2];
    const float* atts1   = (const float*)d_in[3];
    const float* attd1   = (const float*)d_in[4];
    const float* b1      = (const float*)d_in[5];
    const float* W2      = (const float*)d_in[6];
    const float* atts2   = (const float*)d_in[7];
    const float* attd2   = (const float*)d_in[8];
    const float* b2      = (const float*)d_in[9];
    float* out = (float*)d_out;

    char* base = (char*)d_ws;
    size_t off = 0;
    auto take = [&](size_t elems) {
        void* p = base + off;
        off = (off + elems * 4 + 255) & ~(size_t)255;
        return p;
    };
    unsigned* flag = (unsigned*)take(64);
    int* srcE      = (int*)take(NEDGE);
    int* dstE      = (int*)take(NEDGE);
    int* cnt       = (int*)take(NODES);
    int* fill      = (int*)take(NODES);
    int* rowPtr    = (int*)take(NODES + 1);
    int* csrSrc    = (int*)take(ETOT);
    char* l2base = base + off;       // overlay region: h1 dead by the time L2 runs
    float* h1      = (float*)take((size_t)NODES * F1);
    float* as1     = (float*)take((size_t)NODES * NHEAD);
    float* ad1     = (float*)take((size_t)NODES * NHEAD);
    float* m1      = (float*)take((size_t)NODES * NHEAD);
    float* den1    = (float*)take((size_t)NODES * NHEAD);
    float* out1    = (float*)take((size_t)NODES * F1);

    size_t o2 = 0;
    auto take2 = [&](size_t elems) {
        void* p = l2base + o2;
        o2 = (o2 + elems * 4 + 255) & ~(size_t)255;
        return p;
    };
    float* h2   = (float*)take2((size_t)NODES * NC);
    float* as2  = (float*)take2(NODES);
    float* ad2  = (float*)take2(NODES);
    float* m2   = (float*)take2(NODES);
    float* den2 = (float*)take2(NODES);

    hipMemsetAsync(flag, 0, 4, stream);
    hipMemsetAsync(cnt, 0, (size_t)NODES * 4, stream);
    hipMemsetAsync(fill, 0, (size_t)NODES * 4, stream);

    detect_k<<<1, 256, 0, stream>>>(eidx, flag);
    convert_k<<<(NEDGE + 255) / 256, 256, 0, stream>>>(eidx, srcE, dstE, flag);

    // CSR build (by destination)
    hist_k<<<(ETOT + 255) / 256, 256, 0, stream>>>(dstE, cnt);
    scan_k<<<1, 1024, 0, stream>>>(cnt, rowPtr);
    scatter_k<<<(ETOT + 255) / 256, 256, 0, stream>>>(srcE, dstE, rowPtr, fill, csrSrc);

    // Layer 1
    gemm1<<<(NODES + 31) / 32, 256, 0, stream>>>(x, W1, h1);
    a1k<<<(NODES * NHEAD + 255) / 256, 256, 0, stream>>>(h1, atts1, attd1, as1, ad1);
    attn1<<<(NODES * NHEAD + 255) / 256, 256, 0, stream>>>(rowPtr, csrSrc, as1, ad1, m1, den1);
    msg1<<<NODES, 128, 0, stream>>>(rowPtr, csrSrc, as1, ad1, m1, den1, h1, b1, out1);

    // Layer 2 (h2 etc. overlay dead h1)
    gemm2<<<(NODES + 7) / 8, 320, 0, stream>>>(out1, W2, h2);
    a2k<<<(NODES + 255) / 256, 256, 0, stream>>>(h2, atts2, attd2, as2, ad2);
    attn2<<<(NODES + 255) / 256, 256, 0, stream>>>(rowPtr, csrSrc, as2, ad2, m2, den2);
    msg2<<<(NODES + 3) / 4, 256, 0, stream>>>(rowPtr, csrSrc, as2, ad2, m2, den2, h2, b2, out);
}

// Round 3
// 469.892 us; speedup vs baseline: 3.0083x; 1.3336x over previous
//
#include <hip/hip_runtime.h>
#include <math.h>

#define NODES 50000
#define NEDGE 800000
#define ETOT  (NEDGE + NODES)   // edges + self loops = 850000
#define NF    256
#define F1    128               // HEADS*NHID
#define NHEAD 8
#define NHID  16
#define NC    40

__device__ __forceinline__ float lrelu(float v) { return v > 0.f ? v : 0.2f * v; }
__device__ __forceinline__ float bflo(unsigned u) { return __uint_as_float(u << 16); }
__device__ __forceinline__ float bfhi(unsigned u) { return __uint_as_float(u & 0xffff0000u); }
__device__ __forceinline__ unsigned short f2bf(float f) {
    unsigned u = __float_as_uint(f);
    unsigned r = u + 0x7fffu + ((u >> 16) & 1u);   // RNE
    return (unsigned short)(r >> 16);
}

// ---------- edge index dtype detect + normalize ----------
__global__ void detect_k(const unsigned* __restrict__ u, unsigned* __restrict__ flag) {
    int t = threadIdx.x;              // 256 threads
    if (u[2 * t + 1] != 0u) atomicOr(flag, 1u);   // nonzero hi-word pattern => int32 data
}
__global__ void convert_k(const unsigned* __restrict__ u, int* __restrict__ srcE,
                          int* __restrict__ dstE, const unsigned* __restrict__ flag) {
    int e = blockIdx.x * 256 + threadIdx.x;
    if (e >= NEDGE) return;
    if (*flag) {  // int32 layout [2][E]
        srcE[e] = (int)u[e];
        dstE[e] = (int)u[NEDGE + e];
    } else {      // int64 layout [2][E], take lo words
        srcE[e] = (int)u[2 * e];
        dstE[e] = (int)u[2 * NEDGE + 2 * e];
    }
}

// ---------- CSR build ----------
__global__ void hist_k(const int* __restrict__ dstE, int* __restrict__ cnt) {
    int e = blockIdx.x * 256 + threadIdx.x;
    if (e >= ETOT) return;
    int d = (e < NEDGE) ? dstE[e] : e - NEDGE;
    atomicAdd(&cnt[d], 1);
}

__global__ __launch_bounds__(1024) void scan_k(const int* __restrict__ cnt,
                                               int* __restrict__ rowPtr) {
    __shared__ int part[1024];
    const int CH = 49;   // 1024*49 = 50176 >= NODES
    int t = threadIdx.x;
    int beg = t * CH;
    int sum = 0;
    for (int i = 0; i < CH; ++i) {
        int idx = beg + i;
        sum += (idx < NODES) ? cnt[idx] : 0;
    }
    part[t] = sum;
    __syncthreads();
    for (int off = 1; off < 1024; off <<= 1) {
        int v = (t >= off) ? part[t - off] : 0;
        __syncthreads();
        part[t] += v;
        __syncthreads();
    }
    int excl = part[t] - sum;
    int running = excl;
    for (int i = 0; i < CH; ++i) {
        int idx = beg + i;
        if (idx < NODES) {
            rowPtr[idx] = running;
            running += cnt[idx];
        }
    }
    if (t == 1023) rowPtr[NODES] = part[1023];
}

__global__ void scatter_k(const int* __restrict__ srcE, const int* __restrict__ dstE,
                          const int* __restrict__ rowPtr, int* __restrict__ fill,
                          int* __restrict__ csrSrc) {
    int e = blockIdx.x * 256 + threadIdx.x;
    if (e >= ETOT) return;
    int s, d;
    if (e < NEDGE) { s = srcE[e]; d = dstE[e]; } else { s = d = e - NEDGE; }
    int pos = rowPtr[d] + atomicAdd(&fill[d], 1);
    csrSrc[pos] = s;
}

// ---------- GEMM1: x[N,256] @ W1[256,128] -> h1b (bf16) + fused a1k ----------
__global__ __launch_bounds__(256) void gemm1(const float* __restrict__ x,
                                             const float* __restrict__ W,
                                             const float* __restrict__ atts1,
                                             const float* __restrict__ attd1,
                                             unsigned short* __restrict__ h1b,
                                             float* __restrict__ as1,
                                             float* __restrict__ ad1) {
    __shared__ float xs[32][NF];  // 32 KB
    int t = threadIdx.x;
    int base = blockIdx.x * 32;
#pragma unroll
    for (int r = 0; r < 8; ++r) {
        int idx = r * 256 + t;       // float4 index
        int row = idx >> 6;
        int c4 = idx & 63;
        int n = base + row;
        float4 v = make_float4(0.f, 0.f, 0.f, 0.f);
        if (n < NODES) v = ((const float4*)(x + (size_t)n * NF))[c4];
        ((float4*)(&xs[row][0]))[c4] = v;
    }
    __syncthreads();
    int tc = t & 31;   // column group: cols c0..c0+3
    int ng = t >> 5;   // node group 0..7 (4 nodes each)
    int c0 = tc * 4;
    float acc[4][4];
#pragma unroll
    for (int j = 0; j < 4; ++j)
#pragma unroll
        for (int i = 0; i < 4; ++i) acc[j][i] = 0.f;

    for (int k4 = 0; k4 < NF / 4; ++k4) {
        float4 xv[4];
#pragma unroll
        for (int j = 0; j < 4; ++j)
            xv[j] = *(const float4*)(&xs[ng * 4 + j][k4 * 4]);
        const float* wp = W + (size_t)k4 * 4 * F1 + c0;
#pragma unroll
        for (int dk = 0; dk < 4; ++dk) {
            float4 wv = *(const float4*)(wp + dk * F1);
#pragma unroll
            for (int j = 0; j < 4; ++j) {
                float xj = (dk == 0) ? xv[j].x : (dk == 1) ? xv[j].y : (dk == 2) ? xv[j].z : xv[j].w;
                acc[j][0] += xj * wv.x;
                acc[j][1] += xj * wv.y;
                acc[j][2] += xj * wv.z;
                acc[j][3] += xj * wv.w;
            }
        }
    }
    // store bf16 h1
#pragma unroll
    for (int j = 0; j < 4; ++j) {
        int n = base + ng * 4 + j;
        if (n < NODES) {
            ushort4 o;
            o.x = f2bf(acc[j][0]); o.y = f2bf(acc[j][1]);
            o.z = f2bf(acc[j][2]); o.w = f2bf(acc[j][3]);
            *(ushort4*)(h1b + (size_t)n * F1 + c0) = o;
        }
    }
    // fused a1k: as1[n,h] = sum_c h[n,c]*atts1[c] (per head), same for ad1
    __syncthreads();            // done reading xs in k-loop
    float* shs = (float*)xs;    // [32 nodes][32 tc]
    float* shdd = shs + 1024;
    float4 wa = *(const float4*)(atts1 + c0);
    float4 wd = *(const float4*)(attd1 + c0);
#pragma unroll
    for (int j = 0; j < 4; ++j) {
        int nl = ng * 4 + j;
        shs[nl * 32 + tc]  = acc[j][0] * wa.x + acc[j][1] * wa.y + acc[j][2] * wa.z + acc[j][3] * wa.w;
        shdd[nl * 32 + tc] = acc[j][0] * wd.x + acc[j][1] * wd.y + acc[j][2] * wd.z + acc[j][3] * wd.w;
    }
    __syncthreads();
    int nl = t >> 3, h = t & 7, n = base + nl;
    if (n < NODES) {
        const float* ps = shs + nl * 32 + h * 4;
        const float* pd = shdd + nl * 32 + h * 4;
        as1[(size_t)n * NHEAD + h] = ps[0] + ps[1] + ps[2] + ps[3];
        ad1[(size_t)n * NHEAD + h] = pd[0] + pd[1] + pd[2] + pd[3];
    }
}

// ---------- L1 fused flash gather: wave per dst, online softmax, bias+ELU ----------
__global__ __launch_bounds__(256) void msg1(const int* __restrict__ rowPtr,
                                            const int* __restrict__ csrSrc,
                                            const float* __restrict__ as1,
                                            const float* __restrict__ ad1,
                                            const unsigned short* __restrict__ h1b,
                                            const float* __restrict__ b1,
                                            float* __restrict__ out1) {
    int d = blockIdx.x * 4 + (threadIdx.x >> 6);
    if (d >= NODES) return;
    int lane = threadIdx.x & 63;
    int h = lane >> 3;                      // channels 2*lane, 2*lane+1 are in head lane>>3
    float adv = ad1[(size_t)d * NHEAD + h];
    int rs = rowPtr[d], re = rowPtr[d + 1];
    float m = -1e30f, den = 0.f, acc0 = 0.f, acc1 = 0.f;
    int s = csrSrc[rs];
    float av = as1[(size_t)s * NHEAD + h];
    unsigned hv = *(const unsigned*)(h1b + (size_t)s * F1 + lane * 2);
    for (int j = rs; j < re; ++j) {
        float avn = 0.f; unsigned hvn = 0u;
        if (j + 1 < re) {
            int sn = csrSrc[j + 1];
            avn = as1[(size_t)sn * NHEAD + h];
            hvn = *(const unsigned*)(h1b + (size_t)sn * F1 + lane * 2);
        }
        float l = lrelu(av + adv);
        float mn = fmaxf(m, l);
        float f = __expf(m - mn);
        float p = __expf(l - mn);
        den = den * f + p;
        m = mn;
        acc0 = acc0 * f + p * bflo(hv);
        acc1 = acc1 * f + p * bfhi(hv);
        av = avn; hv = hvn;
    }
    float invd = 1.f / (den + 1e-16f);
    float2 bl = *(const float2*)(b1 + lane * 2);
    float v0 = acc0 * invd + bl.x;
    float v1 = acc1 * invd + bl.y;
    v0 = v0 > 0.f ? v0 : expm1f(v0);
    v1 = v1 > 0.f ? v1 : expm1f(v1);
    *(float2*)(out1 + (size_t)d * F1 + lane * 2) = make_float2(v0, v1);
}

// ---------- GEMM2: out1[N,128] @ W2[128,40] -> h2b (bf16) + fused a2k ----------
__global__ __launch_bounds__(320) void gemm2(const float* __restrict__ a,
                                             const float* __restrict__ W,
                                             const float* __restrict__ atts2,
                                             const float* __restrict__ attd2,
                                             unsigned short* __restrict__ h2b,
                                             float* __restrict__ as2,
                                             float* __restrict__ ad2) {
    __shared__ float xs[8][132];
    int t = threadIdx.x;
    int base = blockIdx.x * 8;
    if (t < 256) {
        int row = t >> 5, c4 = t & 31;
        int n = base + row;
        float4 v = make_float4(0.f, 0.f, 0.f, 0.f);
        if (n < NODES) v = ((const float4*)(a + (size_t)n * F1))[c4];
        *(float4*)(&xs[row][c4 * 4]) = v;
    }
    __syncthreads();
    int n = t / 40, c = t % 40;
    float acc = 0.f;
    for (int k4 = 0; k4 < 32; ++k4) {
        float4 xv = *(const float4*)(&xs[n][k4 * 4]);
        const float* wp = W + (size_t)k4 * 4 * NC + c;
        acc += xv.x * wp[0];
        acc += xv.y * wp[NC];
        acc += xv.z * wp[2 * NC];
        acc += xv.w * wp[3 * NC];
    }
    int node = base + n;
    if (node < NODES) h2b[(size_t)node * NC + c] = f2bf(acc);
    // fused a2k
    __syncthreads();            // xs reads done
    float* ss = (float*)xs;     // [8][40]
    float* sd = ss + 320;
    ss[n * 40 + c] = acc * atts2[c];
    sd[n * 40 + c] = acc * attd2[c];
    __syncthreads();
    if (t < 16) {
        int which = t >> 3, nn = t & 7;
        int node2 = base + nn;
        if (node2 < NODES) {
            const float* p = (which ? sd : ss) + nn * 40;
            float sum = 0.f;
            for (int q = 0; q < 40; ++q) sum += p[q];
            if (which) ad2[node2] = sum; else as2[node2] = sum;
        }
    }
}

// ---------- L2 fused flash gather: wave per dst, bias + log_softmax ----------
__global__ __launch_bounds__(256) void msg2(const int* __restrict__ rowPtr,
                                            const int* __restrict__ csrSrc,
                                            const float* __restrict__ as2,
                                            const float* __restrict__ ad2,
                                            const unsigned short* __restrict__ h2b,
                                            const float* __restrict__ b2,
                                            float* __restrict__ out) {
    int d = blockIdx.x * 4 + (threadIdx.x >> 6);
    if (d >= NODES) return;
    int lane = threadIdx.x & 63;
    bool act = lane < 20;                   // channels 2*lane, 2*lane+1
    float adv = ad2[d];
    int rs = rowPtr[d], re = rowPtr[d + 1];
    float m = -1e30f, den = 0.f, acc0 = 0.f, acc1 = 0.f;
    int s = csrSrc[rs];
    float av = as2[s];
    unsigned hv = act ? *(const unsigned*)(h2b + (size_t)s * NC + lane * 2) : 0u;
    for (int j = rs; j < re; ++j) {
        float avn = 0.f; unsigned hvn = 0u;
        if (j + 1 < re) {
            int sn = csrSrc[j + 1];
            avn = as2[sn];
            if (act) hvn = *(const unsigned*)(h2b + (size_t)sn * NC + lane * 2);
        }
        float l = lrelu(av + adv);
        float mn = fmaxf(m, l);
        float f = __expf(m - mn);
        float p = __expf(l - mn);
        den = den * f + p;
        m = mn;
        acc0 = acc0 * f + p * bflo(hv);
        acc1 = acc1 * f + p * bfhi(hv);
        av = avn; hv = hvn;
    }
    float invd = 1.f / (den + 1e-16f);
    float v0 = -1e30f, v1 = -1e30f;
    if (act) {
        float2 bl = *(const float2*)(b2 + lane * 2);
        v0 = acc0 * invd + bl.x;
        v1 = acc1 * invd + bl.y;
    }
    float mm = fmaxf(v0, v1);
#pragma unroll
    for (int off = 32; off; off >>= 1) mm = fmaxf(mm, __shfl_xor(mm, off, 64));
    float e = act ? (expf(v0 - mm) + expf(v1 - mm)) : 0.f;
#pragma unroll
    for (int off = 32; off; off >>= 1) e += __shfl_xor(e, off, 64);
    float lse = mm + logf(e);
    if (act) *(float2*)(out + (size_t)d * NC + lane * 2) = make_float2(v0 - lse, v1 - lse);
}

extern "C" void kernel_launch(void* const* d_in, const int* in_sizes, int n_in,
                              void* d_out, int out_size, void* d_ws, size_t ws_size,
                              hipStream_t stream) {
    const float* x       = (const float*)d_in[0];
    const unsigned* eidx = (const unsigned*)d_in[1];
    const float* W1      = (const float*)d_in[2];
    const float* atts1   = (const float*)d_in[3];
    const float* attd1   = (const float*)d_in[4];
    const float* b1      = (const float*)d_in[5];
    const float* W2      = (const float*)d_in[6];
    const float* atts2   = (const float*)d_in[7];
    const float* attd2   = (const float*)d_in[8];
    const float* b2      = (const float*)d_in[9];
    float* out = (float*)d_out;

    char* base = (char*)d_ws;
    size_t off = 0;
    auto takeB = [&](size_t bytes) {
        void* p = base + off;
        off = (off + bytes + 255) & ~(size_t)255;
        return p;
    };
    unsigned* flag = (unsigned*)takeB(256);
    int* srcE      = (int*)takeB((size_t)NEDGE * 4);
    int* dstE      = (int*)takeB((size_t)NEDGE * 4);
    int* cnt       = (int*)takeB((size_t)NODES * 4);
    int* fill      = (int*)takeB((size_t)NODES * 4);
    int* rowPtr    = (int*)takeB((size_t)(NODES + 1) * 4);
    int* csrSrc    = (int*)takeB((size_t)ETOT * 4);
    char* l2base = base + off;   // overlay: (h1b, as1, ad1) dead by layer 2
    unsigned short* h1b = (unsigned short*)takeB((size_t)NODES * F1 * 2);
    float* as1     = (float*)takeB((size_t)NODES * NHEAD * 4);
    float* ad1     = (float*)takeB((size_t)NODES * NHEAD * 4);
    float* out1    = (float*)takeB((size_t)NODES * F1 * 4);

    size_t o2 = 0;
    auto take2 = [&](size_t bytes) {
        void* p = l2base + o2;
        o2 = (o2 + bytes + 255) & ~(size_t)255;
        return p;
    };
    unsigned short* h2b = (unsigned short*)takeB(0);  // placeholder silence
    h2b          = (unsigned short*)take2((size_t)NODES * NC * 2 + 256);  // +pad: inactive-lane overreads
    float* as2   = (float*)take2((size_t)NODES * 4);
    float* ad2   = (float*)take2((size_t)NODES * 4);

    hipMemsetAsync(flag, 0, 4, stream);
    hipMemsetAsync(cnt, 0, (size_t)NODES * 4, stream);
    hipMemsetAsync(fill, 0, (size_t)NODES * 4, stream);

    detect_k<<<1, 256, 0, stream>>>(eidx, flag);
    convert_k<<<(NEDGE + 255) / 256, 256, 0, stream>>>(eidx, srcE, dstE, flag);

    // CSR build (by destination)
    hist_k<<<(ETOT + 255) / 256, 256, 0, stream>>>(dstE, cnt);
    scan_k<<<1, 1024, 0, stream>>>(cnt, rowPtr);
    scatter_k<<<(ETOT + 255) / 256, 256, 0, stream>>>(srcE, dstE, rowPtr, fill, csrSrc);

    // Layer 1
    gemm1<<<(NODES + 31) / 32, 256, 0, stream>>>(x, W1, atts1, attd1, h1b, as1, ad1);
    msg1<<<(NODES + 3) / 4, 256, 0, stream>>>(rowPtr, csrSrc, as1, ad1, h1b, b1, out1);

    // Layer 2 (h2b/as2/ad2 overlay dead h1b/as1/ad1)
    gemm2<<<(NODES + 7) / 8, 320, 0, stream>>>(out1, W2, atts2, attd2, h2b, as2, ad2);
    msg2<<<(NODES + 3) / 4, 256, 0, stream>>>(rowPtr, csrSrc, as2, ad2, h2b, b2, out);
}

// Round 4
// 391.276 us; speedup vs baseline: 3.6127x; 1.2009x over previous
//
#include <hip/hip_runtime.h>
#include <math.h>

#define NODES 50000
#define NEDGE 800000
#define ETOT  (NEDGE + NODES)   // edges + self loops = 850000
#define NF    256
#define F1    128               // HEADS*NHID
#define NHEAD 8
#define NHID  16
#define NC    40

__device__ __forceinline__ float lrelu(float v) { return v > 0.f ? v : 0.2f * v; }
__device__ __forceinline__ float bflo(unsigned u) { return __uint_as_float(u << 16); }
__device__ __forceinline__ float bfhi(unsigned u) { return __uint_as_float(u & 0xffff0000u); }
__device__ __forceinline__ unsigned short f2bf(float f) {
    unsigned u = __float_as_uint(f);
    unsigned r = u + 0x7fffu + ((u >> 16) & 1u);   // RNE
    return (unsigned short)(r >> 16);
}

// ---------- edge index dtype detect ----------
__global__ void detect_k(const unsigned* __restrict__ u, unsigned* __restrict__ flag) {
    int t = threadIdx.x;              // 256 threads
    if (u[2 * t + 1] != 0u) atomicOr(flag, 1u);   // nonzero hi-word pattern => int32 data
}

// ---------- CSR build (reads edge_index directly) ----------
__global__ void hist_k(const unsigned* __restrict__ u, const unsigned* __restrict__ flag,
                       int* __restrict__ cnt) {
    int e = blockIdx.x * 256 + threadIdx.x;
    if (e >= ETOT) return;
    int d;
    if (e < NEDGE) d = (*flag) ? (int)u[NEDGE + e] : (int)u[2 * NEDGE + 2 * e];
    else d = e - NEDGE;
    atomicAdd(&cnt[d], 1);
}

__global__ __launch_bounds__(1024) void scan_k(const int* __restrict__ cnt,
                                               int* __restrict__ rowPtr) {
    __shared__ int part[1024];
    const int CH = 49;   // 1024*49 = 50176 >= NODES
    int t = threadIdx.x;
    int beg = t * CH;
    int sum = 0;
    for (int i = 0; i < CH; ++i) {
        int idx = beg + i;
        sum += (idx < NODES) ? cnt[idx] : 0;
    }
    part[t] = sum;
    __syncthreads();
    for (int off = 1; off < 1024; off <<= 1) {
        int v = (t >= off) ? part[t - off] : 0;
        __syncthreads();
        part[t] += v;
        __syncthreads();
    }
    int excl = part[t] - sum;
    int running = excl;
    for (int i = 0; i < CH; ++i) {
        int idx = beg + i;
        if (idx < NODES) {
            rowPtr[idx] = running;
            running += cnt[idx];
        }
    }
    if (t == 1023) rowPtr[NODES] = part[1023];
}

__global__ void scatter_k(const unsigned* __restrict__ u, const unsigned* __restrict__ flag,
                          const int* __restrict__ rowPtr, int* __restrict__ fill,
                          int* __restrict__ csrSrc) {
    int e = blockIdx.x * 256 + threadIdx.x;
    if (e >= ETOT) return;
    int s, d;
    if (e < NEDGE) {
        if (*flag) { s = (int)u[e]; d = (int)u[NEDGE + e]; }
        else       { s = (int)u[2 * e]; d = (int)u[2 * NEDGE + 2 * e]; }
    } else s = d = e - NEDGE;
    int pos = rowPtr[d] + atomicAdd(&fill[d], 1);
    csrSrc[pos] = s;
}

// ---------- GEMM1: x[N,256] @ W1[256,128] -> h1b (bf16) + fused a1k ----------
__global__ __launch_bounds__(256) void gemm1(const float* __restrict__ x,
                                             const float* __restrict__ W,
                                             const float* __restrict__ atts1,
                                             const float* __restrict__ attd1,
                                             unsigned short* __restrict__ h1b,
                                             float* __restrict__ as1,
                                             float* __restrict__ ad1) {
    __shared__ float xs[32][NF];  // 32 KB
    int t = threadIdx.x;
    int base = blockIdx.x * 32;
#pragma unroll
    for (int r = 0; r < 8; ++r) {
        int idx = r * 256 + t;       // float4 index
        int row = idx >> 6;
        int c4 = idx & 63;
        int n = base + row;
        float4 v = make_float4(0.f, 0.f, 0.f, 0.f);
        if (n < NODES) v = ((const float4*)(x + (size_t)n * NF))[c4];
        ((float4*)(&xs[row][0]))[c4] = v;
    }
    __syncthreads();
    int tc = t & 31;   // column group: cols c0..c0+3
    int ng = t >> 5;   // node group 0..7 (4 nodes each)
    int c0 = tc * 4;
    float acc[4][4];
#pragma unroll
    for (int j = 0; j < 4; ++j)
#pragma unroll
        for (int i = 0; i < 4; ++i) acc[j][i] = 0.f;

    for (int k4 = 0; k4 < NF / 4; ++k4) {
        float4 xv[4];
#pragma unroll
        for (int j = 0; j < 4; ++j)
            xv[j] = *(const float4*)(&xs[ng * 4 + j][k4 * 4]);
        const float* wp = W + (size_t)k4 * 4 * F1 + c0;
#pragma unroll
        for (int dk = 0; dk < 4; ++dk) {
            float4 wv = *(const float4*)(wp + dk * F1);
#pragma unroll
            for (int j = 0; j < 4; ++j) {
                float xj = (dk == 0) ? xv[j].x : (dk == 1) ? xv[j].y : (dk == 2) ? xv[j].z : xv[j].w;
                acc[j][0] += xj * wv.x;
                acc[j][1] += xj * wv.y;
                acc[j][2] += xj * wv.z;
                acc[j][3] += xj * wv.w;
            }
        }
    }
#pragma unroll
    for (int j = 0; j < 4; ++j) {
        int n = base + ng * 4 + j;
        if (n < NODES) {
            ushort4 o;
            o.x = f2bf(acc[j][0]); o.y = f2bf(acc[j][1]);
            o.z = f2bf(acc[j][2]); o.w = f2bf(acc[j][3]);
            *(ushort4*)(h1b + (size_t)n * F1 + c0) = o;
        }
    }
    // fused a1k
    __syncthreads();
    float* shs = (float*)xs;    // [32 nodes][32 tc]
    float* shdd = shs + 1024;
    float4 wa = *(const float4*)(atts1 + c0);
    float4 wd = *(const float4*)(attd1 + c0);
#pragma unroll
    for (int j = 0; j < 4; ++j) {
        int nl = ng * 4 + j;
        shs[nl * 32 + tc]  = acc[j][0] * wa.x + acc[j][1] * wa.y + acc[j][2] * wa.z + acc[j][3] * wa.w;
        shdd[nl * 32 + tc] = acc[j][0] * wd.x + acc[j][1] * wd.y + acc[j][2] * wd.z + acc[j][3] * wd.w;
    }
    __syncthreads();
    int nl = t >> 3, h = t & 7, n = base + nl;
    if (n < NODES) {
        const float* ps = shs + nl * 32 + h * 4;
        const float* pd = shdd + nl * 32 + h * 4;
        as1[(size_t)n * NHEAD + h] = ps[0] + ps[1] + ps[2] + ps[3];
        ad1[(size_t)n * NHEAD + h] = pd[0] + pd[1] + pd[2] + pd[3];
    }
}

// flash-softmax edge processing step
#define PROC(AV, HV)                                     \
    {                                                    \
        float l = lrelu((AV) + adv);                     \
        float mn = fmaxf(m, l);                          \
        float f = __expf(m - mn);                        \
        float p = __expf(l - mn);                        \
        den = den * f + p;                               \
        m = mn;                                          \
        acc0 = acc0 * f + p * bflo(HV);                  \
        acc1 = acc1 * f + p * bfhi(HV);                  \
    }

// ---------- L1 fused gather + GEMM2 + a2k: wave per dst ----------
__global__ __launch_bounds__(256) void msg1(const int* __restrict__ rowPtr,
                                            const int* __restrict__ csrSrc,
                                            const float* __restrict__ as1,
                                            const float* __restrict__ ad1,
                                            const unsigned short* __restrict__ h1b,
                                            const float* __restrict__ b1,
                                            const float* __restrict__ W2,
                                            const float* __restrict__ atts2,
                                            const float* __restrict__ attd2,
                                            unsigned short* __restrict__ h2b,
                                            float* __restrict__ as2,
                                            float* __restrict__ ad2) {
    __shared__ float W2t[NC][132];      // transposed, padded (16B-aligned rows)
    __shared__ float rowbuf[4][F1];
    int t = threadIdx.x;
    // stage W2 transposed: 5120 floats
    for (int i = t; i < 1280; i += 256) {
        float4 v = ((const float4*)W2)[i];
        int flat = i * 4;
#pragma unroll
        for (int q = 0; q < 4; ++q) {
            int f = flat + q;
            W2t[f % NC][f / NC] = ((const float*)&v)[q];
        }
    }
    __syncthreads();

    int wid = t >> 6, lane = t & 63;
    int d = blockIdx.x * 4 + wid;       // grid exact: always < NODES
    int h = lane >> 3;
    float adv = ad1[(size_t)d * NHEAD + h];
    int rs = rowPtr[d], re = rowPtr[d + 1];
    float m = -1e30f, den = 0.f, acc0 = 0.f, acc1 = 0.f;

    for (int cb = rs; cb < re; cb += 64) {
        int cn = min(64, re - cb);
        int svi = cb + lane;
        int sv = (svi < re) ? csrSrc[svi] : 0;
#define LDE(II, AV, HV)                                                         \
        {                                                                       \
            int ii = (II);                                                      \
            bool g = ii < cn; /* wave-uniform */                                \
            int ss = __shfl(sv, g ? ii : 0, 64);                                \
            AV = -1e30f; HV = 0u;                                               \
            if (g) {                                                            \
                AV = as1[(size_t)ss * NHEAD + h];                               \
                HV = *(const unsigned*)(h1b + (size_t)ss * F1 + (lane << 1));   \
            }                                                                   \
        }
        float avA, avB, avC, avD;
        unsigned hvA, hvB, hvC, hvD;
        LDE(0, avA, hvA); LDE(1, avB, hvB); LDE(2, avC, hvC); LDE(3, avD, hvD);
        for (int i = 0; i < cn; i += 4) {
            float tA, tB, tC, tD;
            unsigned uA, uB, uC, uD;
            LDE(i + 4, tA, uA); LDE(i + 5, tB, uB);
            LDE(i + 6, tC, uC); LDE(i + 7, tD, uD);
            PROC(avA, hvA); PROC(avB, hvB); PROC(avC, hvC); PROC(avD, hvD);
            avA = tA; avB = tB; avC = tC; avD = tD;
            hvA = uA; hvB = uB; hvC = uC; hvD = uD;
        }
#undef LDE
    }
    float invd = 1.f / (den + 1e-16f);
    float2 bl = *(const float2*)(b1 + lane * 2);
    float v0 = acc0 * invd + bl.x;
    float v1 = acc1 * invd + bl.y;
    v0 = v0 > 0.f ? v0 : expm1f(v0);
    v1 = v1 > 0.f ? v1 : expm1f(v1);
    *(float2*)(&rowbuf[wid][lane * 2]) = make_float2(v0, v1);

    // fused GEMM2 row: h2[c] = row . W2[:,c]   (lanes 0..39)
    float h2c = 0.f;
    if (lane < NC) {
#pragma unroll
        for (int k4 = 0; k4 < 32; ++k4) {
            float4 rv = *(const float4*)(&rowbuf[wid][k4 * 4]);
            float4 wv = *(const float4*)(&W2t[lane][k4 * 4]);
            h2c += rv.x * wv.x + rv.y * wv.y + rv.z * wv.z + rv.w * wv.w;
        }
        h2b[(size_t)d * NC + lane] = f2bf(h2c);
    }
    // fused a2k
    float cs = (lane < NC) ? h2c * atts2[lane] : 0.f;
    float cd = (lane < NC) ? h2c * attd2[lane] : 0.f;
#pragma unroll
    for (int off = 32; off; off >>= 1) {
        cs += __shfl_xor(cs, off, 64);
        cd += __shfl_xor(cd, off, 64);
    }
    if (lane == 0) { as2[d] = cs; ad2[d] = cd; }
}

// ---------- L2 fused flash gather: wave per dst, bias + log_softmax ----------
__global__ __launch_bounds__(256) void msg2(const int* __restrict__ rowPtr,
                                            const int* __restrict__ csrSrc,
                                            const float* __restrict__ as2,
                                            const float* __restrict__ ad2,
                                            const unsigned short* __restrict__ h2b,
                                            const float* __restrict__ b2,
                                            float* __restrict__ out) {
    int d = blockIdx.x * 4 + (threadIdx.x >> 6);
    if (d >= NODES) return;
    int lane = threadIdx.x & 63;
    bool act = lane < 20;                   // channels 2*lane, 2*lane+1
    float adv = ad2[d];
    int rs = rowPtr[d], re = rowPtr[d + 1];
    float m = -1e30f, den = 0.f, acc0 = 0.f, acc1 = 0.f;

    for (int cb = rs; cb < re; cb += 64) {
        int cn = min(64, re - cb);
        int svi = cb + lane;
        int sv = (svi < re) ? csrSrc[svi] : 0;
#define LDE(II, AV, HV)                                                         \
        {                                                                       \
            int ii = (II);                                                      \
            bool g = ii < cn;                                                   \
            int ss = __shfl(sv, g ? ii : 0, 64);                                \
            AV = -1e30f; HV = 0u;                                               \
            if (g) {                                                            \
                AV = as2[ss];                                                   \
                if (act) HV = *(const unsigned*)(h2b + (size_t)ss * NC + (lane << 1)); \
            }                                                                   \
        }
        float avA, avB, avC, avD;
        unsigned hvA, hvB, hvC, hvD;
        LDE(0, avA, hvA); LDE(1, avB, hvB); LDE(2, avC, hvC); LDE(3, avD, hvD);
        for (int i = 0; i < cn; i += 4) {
            float tA, tB, tC, tD;
            unsigned uA, uB, uC, uD;
            LDE(i + 4, tA, uA); LDE(i + 5, tB, uB);
            LDE(i + 6, tC, uC); LDE(i + 7, tD, uD);
            PROC(avA, hvA); PROC(avB, hvB); PROC(avC, hvC); PROC(avD, hvD);
            avA = tA; avB = tB; avC = tC; avD = tD;
            hvA = uA; hvB = uB; hvC = uC; hvD = uD;
        }
#undef LDE
    }
    float invd = 1.f / (den + 1e-16f);
    float v0 = -1e30f, v1 = -1e30f;
    if (act) {
        float2 bl = *(const float2*)(b2 + lane * 2);
        v0 = acc0 * invd + bl.x;
        v1 = acc1 * invd + bl.y;
    }
    float mm = fmaxf(v0, v1);
#pragma unroll
    for (int off = 32; off; off >>= 1) mm = fmaxf(mm, __shfl_xor(mm, off, 64));
    float e = act ? (expf(v0 - mm) + expf(v1 - mm)) : 0.f;
#pragma unroll
    for (int off = 32; off; off >>= 1) e += __shfl_xor(e, off, 64);
    float lse = mm + logf(e);
    if (act) *(float2*)(out + (size_t)d * NC + lane * 2) = make_float2(v0 - lse, v1 - lse);
}

extern "C" void kernel_launch(void* const* d_in, const int* in_sizes, int n_in,
                              void* d_out, int out_size, void* d_ws, size_t ws_size,
                              hipStream_t stream) {
    const float* x       = (const float*)d_in[0];
    const unsigned* eidx = (const unsigned*)d_in[1];
    const float* W1      = (const float*)d_in[2];
    const float* atts1   = (const float*)d_in[3];
    const float* attd1   = (const float*)d_in[4];
    const float* b1      = (const float*)d_in[5];
    const float* W2      = (const float*)d_in[6];
    const float* atts2   = (const float*)d_in[7];
    const float* attd2   = (const float*)d_in[8];
    const float* b2      = (const float*)d_in[9];
    float* out = (float*)d_out;

    char* base = (char*)d_ws;
    size_t off = 0;
    auto takeB = [&](size_t bytes) {
        void* p = base + off;
        off = (off + bytes + 255) & ~(size_t)255;
        return p;
    };
    unsigned* flag = (unsigned*)takeB(256);
    int* cnt       = (int*)takeB((size_t)NODES * 4);
    int* fill      = (int*)takeB((size_t)NODES * 4);
    int* rowPtr    = (int*)takeB((size_t)(NODES + 1) * 4);
    int* csrSrc    = (int*)takeB((size_t)ETOT * 4);
    unsigned short* h1b = (unsigned short*)takeB((size_t)NODES * F1 * 2);
    float* as1     = (float*)takeB((size_t)NODES * NHEAD * 4);
    float* ad1     = (float*)takeB((size_t)NODES * NHEAD * 4);
    unsigned short* h2b = (unsigned short*)takeB((size_t)NODES * NC * 2 + 256);
    float* as2     = (float*)takeB((size_t)NODES * 4);
    float* ad2     = (float*)takeB((size_t)NODES * 4);

    hipMemsetAsync(flag, 0, 4, stream);
    hipMemsetAsync(cnt, 0, (size_t)NODES * 4, stream);
    hipMemsetAsync(fill, 0, (size_t)NODES * 4, stream);

    detect_k<<<1, 256, 0, stream>>>(eidx, flag);

    // CSR build (by destination), reading edge_index directly
    hist_k<<<(ETOT + 255) / 256, 256, 0, stream>>>(eidx, flag, cnt);
    scan_k<<<1, 1024, 0, stream>>>(cnt, rowPtr);
    scatter_k<<<(ETOT + 255) / 256, 256, 0, stream>>>(eidx, flag, rowPtr, fill, csrSrc);

    // Layer 1 + fused layer-2 projection
    gemm1<<<(NODES + 31) / 32, 256, 0, stream>>>(x, W1, atts1, attd1, h1b, as1, ad1);
    msg1<<<NODES / 4, 256, 0, stream>>>(rowPtr, csrSrc, as1, ad1, h1b, b1,
                                        W2, atts2, attd2, h2b, as2, ad2);

    // Layer 2 gather + log_softmax
    msg2<<<(NODES + 3) / 4, 256, 0, stream>>>(rowPtr, csrSrc, as2, ad2, h2b, b2, out);
}

// Round 5
// 359.149 us; speedup vs baseline: 3.9359x; 1.0895x over previous
//
#include <hip/hip_runtime.h>
#include <math.h>

#define NODES 50000
#define NEDGE 800000
#define ETOT  (NEDGE + NODES)   // edges + self loops = 850000
#define NF    256
#define F1    128               // HEADS*NHID
#define NHEAD 8
#define NHID  16
#define NC    40

__device__ __forceinline__ float bflo(unsigned u) { return __uint_as_float(u << 16); }
__device__ __forceinline__ float bfhi(unsigned u) { return __uint_as_float(u & 0xffff0000u); }
__device__ __forceinline__ unsigned short f2bf(float f) {
    unsigned u = __float_as_uint(f);
    unsigned r = u + 0x7fffu + ((u >> 16) & 1u);   // RNE
    return (unsigned short)(r >> 16);
}
__device__ __forceinline__ unsigned pk2(float a, float b) {
    return (unsigned)f2bf(a) | ((unsigned)f2bf(b) << 16);
}

// ---------- edge index dtype detect ----------
__global__ void detect_k(const unsigned* __restrict__ u, unsigned* __restrict__ flag) {
    int t = threadIdx.x;              // 256 threads
    if (u[2 * t + 1] != 0u) atomicOr(flag, 1u);   // nonzero hi-word pattern => int32 data
}

// ---------- CSR build (reads edge_index directly) ----------
__global__ void hist_k(const unsigned* __restrict__ u, const unsigned* __restrict__ flag,
                       int* __restrict__ cnt) {
    int e = blockIdx.x * 256 + threadIdx.x;
    if (e >= ETOT) return;
    int d;
    if (e < NEDGE) d = (*flag) ? (int)u[NEDGE + e] : (int)u[2 * NEDGE + 2 * e];
    else d = e - NEDGE;
    atomicAdd(&cnt[d], 1);
}

__global__ __launch_bounds__(1024) void scan_k(const int* __restrict__ cnt,
                                               int* __restrict__ rowPtr) {
    __shared__ int part[1024];
    const int CH = 49;   // 1024*49 = 50176 >= NODES
    int t = threadIdx.x;
    int beg = t * CH;
    int sum = 0;
    for (int i = 0; i < CH; ++i) {
        int idx = beg + i;
        sum += (idx < NODES) ? cnt[idx] : 0;
    }
    part[t] = sum;
    __syncthreads();
    for (int off = 1; off < 1024; off <<= 1) {
        int v = (t >= off) ? part[t - off] : 0;
        __syncthreads();
        part[t] += v;
        __syncthreads();
    }
    int excl = part[t] - sum;
    int running = excl;
    for (int i = 0; i < CH; ++i) {
        int idx = beg + i;
        if (idx < NODES) {
            rowPtr[idx] = running;
            running += cnt[idx];
        }
    }
    if (t == 1023) rowPtr[NODES] = part[1023];
}

__global__ void scatter_k(const unsigned* __restrict__ u, const unsigned* __restrict__ flag,
                          const int* __restrict__ rowPtr, int* __restrict__ fill,
                          int* __restrict__ csrSrc) {
    int e = blockIdx.x * 256 + threadIdx.x;
    if (e >= ETOT) return;
    int s, d;
    if (e < NEDGE) {
        if (*flag) { s = (int)u[e]; d = (int)u[NEDGE + e]; }
        else       { s = (int)u[2 * e]; d = (int)u[2 * NEDGE + 2 * e]; }
    } else s = d = e - NEDGE;
    int pos = rowPtr[d] + atomicAdd(&fill[d], 1);
    csrSrc[pos] = s;
}

// ---------- GEMM1: x[N,256] @ W1[256,128] -> h1b (bf16) + fused a1k ----------
__global__ __launch_bounds__(256) void gemm1(const float* __restrict__ x,
                                             const float* __restrict__ W,
                                             const float* __restrict__ atts1,
                                             const float* __restrict__ attd1,
                                             unsigned short* __restrict__ h1b,
                                             float* __restrict__ as1,
                                             float* __restrict__ ad1) {
    __shared__ float xs[32][NF];  // 32 KB
    int t = threadIdx.x;
    int base = blockIdx.x * 32;
#pragma unroll
    for (int r = 0; r < 8; ++r) {
        int idx = r * 256 + t;       // float4 index
        int row = idx >> 6;
        int c4 = idx & 63;
        int n = base + row;
        float4 v = make_float4(0.f, 0.f, 0.f, 0.f);
        if (n < NODES) v = ((const float4*)(x + (size_t)n * NF))[c4];
        ((float4*)(&xs[row][0]))[c4] = v;
    }
    __syncthreads();
    int tc = t & 31;   // column group: cols c0..c0+3
    int ng = t >> 5;   // node group 0..7 (4 nodes each)
    int c0 = tc * 4;
    float acc[4][4];
#pragma unroll
    for (int j = 0; j < 4; ++j)
#pragma unroll
        for (int i = 0; i < 4; ++i) acc[j][i] = 0.f;

    for (int k4 = 0; k4 < NF / 4; ++k4) {
        float4 xv[4];
#pragma unroll
        for (int j = 0; j < 4; ++j)
            xv[j] = *(const float4*)(&xs[ng * 4 + j][k4 * 4]);
        const float* wp = W + (size_t)k4 * 4 * F1 + c0;
#pragma unroll
        for (int dk = 0; dk < 4; ++dk) {
            float4 wv = *(const float4*)(wp + dk * F1);
#pragma unroll
            for (int j = 0; j < 4; ++j) {
                float xj = (dk == 0) ? xv[j].x : (dk == 1) ? xv[j].y : (dk == 2) ? xv[j].z : xv[j].w;
                acc[j][0] += xj * wv.x;
                acc[j][1] += xj * wv.y;
                acc[j][2] += xj * wv.z;
                acc[j][3] += xj * wv.w;
            }
        }
    }
#pragma unroll
    for (int j = 0; j < 4; ++j) {
        int n = base + ng * 4 + j;
        if (n < NODES) {
            ushort4 o;
            o.x = f2bf(acc[j][0]); o.y = f2bf(acc[j][1]);
            o.z = f2bf(acc[j][2]); o.w = f2bf(acc[j][3]);
            *(ushort4*)(h1b + (size_t)n * F1 + c0) = o;
        }
    }
    // fused a1k
    __syncthreads();
    float* shs = (float*)xs;    // [32 nodes][32 tc]
    float* shdd = shs + 1024;
    float4 wa = *(const float4*)(atts1 + c0);
    float4 wd = *(const float4*)(attd1 + c0);
#pragma unroll
    for (int j = 0; j < 4; ++j) {
        int nl = ng * 4 + j;
        shs[nl * 32 + tc]  = acc[j][0] * wa.x + acc[j][1] * wa.y + acc[j][2] * wa.z + acc[j][3] * wa.w;
        shdd[nl * 32 + tc] = acc[j][0] * wd.x + acc[j][1] * wd.y + acc[j][2] * wd.z + acc[j][3] * wd.w;
    }
    __syncthreads();
    int nl = t >> 3, h = t & 7, n = base + nl;
    if (n < NODES) {
        const float* ps = shs + nl * 32 + h * 4;
        const float* pd = shdd + nl * 32 + h * 4;
        as1[(size_t)n * NHEAD + h] = ps[0] + ps[1] + ps[2] + ps[3];
        ad1[(size_t)n * NHEAD + h] = pd[0] + pd[1] + pd[2] + pd[3];
    }
}

// no-max softmax step: 8 channels per lane
#define PROC8(AV, HV)                                    \
    {                                                    \
        float l = (AV) + adv;                            \
        l = l > 0.f ? l : 0.2f * l;                      \
        float p = __expf(l);                             \
        den += p;                                        \
        acc[0] += p * bflo(HV.x); acc[1] += p * bfhi(HV.x); \
        acc[2] += p * bflo(HV.y); acc[3] += p * bfhi(HV.y); \
        acc[4] += p * bflo(HV.z); acc[5] += p * bfhi(HV.z); \
        acc[6] += p * bflo(HV.w); acc[7] += p * bfhi(HV.w); \
    }

// ---------- L1 gather: wave per dst, 4 edges/step, 8ch/lane, bias+ELU -> bf16 ----------
__global__ __launch_bounds__(256) void msg1(const int* __restrict__ rowPtr,
                                            const int* __restrict__ csrSrc,
                                            const float* __restrict__ as1,
                                            const float* __restrict__ ad1,
                                            const unsigned short* __restrict__ h1b,
                                            const float* __restrict__ b1,
                                            unsigned short* __restrict__ out1b) {
    int t = threadIdx.x;
    int wid = t >> 6, lane = t & 63;
    int d = blockIdx.x * 4 + wid;        // grid exact (50000/4)
    int g = lane >> 4;                    // edge subgroup 0..3
    int cl = lane & 15;                   // channel lane: ch 8*cl..8*cl+7
    int h = cl >> 1;                      // head
    float adv = ad1[(size_t)d * NHEAD + h];
    int rs = rowPtr[d], re = rowPtr[d + 1];
    float den = 0.f;
    float acc[8];
#pragma unroll
    for (int k = 0; k < 8; ++k) acc[k] = 0.f;

#define LD1(J0, AV, HV)                                               \
    {                                                                 \
        int j = (J0) + g;                                             \
        bool val = j < re;                                            \
        int jj = val ? j : re - 1;                                    \
        int ss = csrSrc[jj];                                          \
        AV = val ? as1[(size_t)ss * NHEAD + h] : -1e30f;              \
        HV = *(const uint4*)(h1b + (size_t)ss * F1 + cl * 8);         \
    }

    float av0, av1; uint4 hv0, hv1;
    LD1(rs, av0, hv0);
    LD1(rs + 4, av1, hv1);
    for (int j0 = rs; j0 < re; j0 += 8) {
        float ta, tb; uint4 ha, hb;
        LD1(j0 + 8, ta, ha);
        LD1(j0 + 12, tb, hb);
        PROC8(av0, hv0);
        PROC8(av1, hv1);
        av0 = ta; hv0 = ha; av1 = tb; hv1 = hb;
    }
#undef LD1

    // reduce across the 4 edge-groups
#pragma unroll
    for (int k = 0; k < 8; ++k) {
        acc[k] += __shfl_xor(acc[k], 16, 64);
        acc[k] += __shfl_xor(acc[k], 32, 64);
    }
    den += __shfl_xor(den, 16, 64);
    den += __shfl_xor(den, 32, 64);
    float invd = 1.f / (den + 1e-16f);

    if (g == 0) {
        const float4* bp = (const float4*)(b1 + cl * 8);
        float4 ba = bp[0], bb = bp[1];
        float v[8];
        v[0] = acc[0] * invd + ba.x; v[1] = acc[1] * invd + ba.y;
        v[2] = acc[2] * invd + ba.z; v[3] = acc[3] * invd + ba.w;
        v[4] = acc[4] * invd + bb.x; v[5] = acc[5] * invd + bb.y;
        v[6] = acc[6] * invd + bb.z; v[7] = acc[7] * invd + bb.w;
#pragma unroll
        for (int k = 0; k < 8; ++k) v[k] = v[k] > 0.f ? v[k] : expm1f(v[k]);
        uint4 o;
        o.x = pk2(v[0], v[1]); o.y = pk2(v[2], v[3]);
        o.z = pk2(v[4], v[5]); o.w = pk2(v[6], v[7]);
        *(uint4*)(out1b + (size_t)d * F1 + cl * 8) = o;
    }
}

// ---------- GEMM2: out1b[N,128]bf16 @ W2[128,40] -> h2b (bf16) + fused a2k ----------
__global__ __launch_bounds__(320) void gemm2k(const unsigned short* __restrict__ a,
                                              const float* __restrict__ W,
                                              const float* __restrict__ atts2,
                                              const float* __restrict__ attd2,
                                              unsigned short* __restrict__ h2b,
                                              float* __restrict__ as2,
                                              float* __restrict__ ad2) {
    __shared__ float xs[8][132];
    __shared__ float red[2][320];
    int t = threadIdx.x;
    int base = blockIdx.x * 8;           // grid exact (50000/8)
    if (t < 256) {
        int row = t >> 5, q = t & 31;
        uint2 u = *(const uint2*)(a + (size_t)(base + row) * F1 + q * 4);
        float4 f;
        f.x = bflo(u.x); f.y = bfhi(u.x); f.z = bflo(u.y); f.w = bfhi(u.y);
        *(float4*)(&xs[row][q * 4]) = f;
    }
    __syncthreads();
    int n = t / 40, c = t % 40;
    float acc = 0.f;
    for (int k4 = 0; k4 < 32; ++k4) {
        float4 xv = *(const float4*)(&xs[n][k4 * 4]);
        const float* wp = W + (size_t)k4 * 4 * NC + c;
        acc += xv.x * wp[0];
        acc += xv.y * wp[NC];
        acc += xv.z * wp[2 * NC];
        acc += xv.w * wp[3 * NC];
    }
    int node = base + n;
    h2b[(size_t)node * NC + c] = f2bf(acc);
    red[0][n * 40 + c] = acc * atts2[c];
    red[1][n * 40 + c] = acc * attd2[c];
    __syncthreads();
    if (t < 16) {
        int which = t >> 3, nn = t & 7;
        const float* p = red[which] + nn * 40;
        float s = 0.f;
        for (int q = 0; q < 40; ++q) s += p[q];
        if (which) ad2[base + nn] = s; else as2[base + nn] = s;
    }
}

// ---------- L2 gather: wave per dst, 8 edges/step, bias + log_softmax ----------
__global__ __launch_bounds__(256) void msg2(const int* __restrict__ rowPtr,
                                            const int* __restrict__ csrSrc,
                                            const float* __restrict__ as2,
                                            const float* __restrict__ ad2,
                                            const unsigned short* __restrict__ h2b,
                                            const float* __restrict__ b2,
                                            float* __restrict__ out) {
    int t = threadIdx.x;
    int wid = t >> 6, lane = t & 63;
    int d = blockIdx.x * 4 + wid;        // grid exact
    int g = lane >> 3;                    // edge subgroup 0..7
    int cl = lane & 7;                    // channel lane; active cl<5 (8 ch each)
    int clc = cl < 5 ? cl : 4;
    bool act = cl < 5;
    float adv = ad2[d];
    int rs = rowPtr[d], re = rowPtr[d + 1];
    float den = 0.f;
    float acc[8];
#pragma unroll
    for (int k = 0; k < 8; ++k) acc[k] = 0.f;

#define LD2(J0, AV, HV)                                               \
    {                                                                 \
        int j = (J0) + g;                                             \
        bool val = j < re;                                            \
        int jj = val ? j : re - 1;                                    \
        int ss = csrSrc[jj];                                          \
        AV = val ? as2[ss] : -1e30f;                                  \
        HV = *(const uint4*)(h2b + (size_t)ss * NC + clc * 8);        \
    }

    float av0, av1; uint4 hv0, hv1;
    LD2(rs, av0, hv0);
    LD2(rs + 8, av1, hv1);
    for (int j0 = rs; j0 < re; j0 += 16) {
        float ta, tb; uint4 ha, hb;
        LD2(j0 + 16, ta, ha);
        LD2(j0 + 24, tb, hb);
        PROC8(av0, hv0);
        PROC8(av1, hv1);
        av0 = ta; hv0 = ha; av1 = tb; hv1 = hb;
    }
#undef LD2

    // reduce across the 8 edge-groups
#pragma unroll
    for (int k = 0; k < 8; ++k) {
        acc[k] += __shfl_xor(acc[k], 8, 64);
        acc[k] += __shfl_xor(acc[k], 16, 64);
        acc[k] += __shfl_xor(acc[k], 32, 64);
    }
    den += __shfl_xor(den, 8, 64);
    den += __shfl_xor(den, 16, 64);
    den += __shfl_xor(den, 32, 64);
    float invd = 1.f / (den + 1e-16f);

    float v[8];
    float mk = -1e30f;
    if (act) {
        const float4* bp = (const float4*)(b2 + cl * 8);
        float4 ba = bp[0], bb = bp[1];
        v[0] = acc[0] * invd + ba.x; v[1] = acc[1] * invd + ba.y;
        v[2] = acc[2] * invd + ba.z; v[3] = acc[3] * invd + ba.w;
        v[4] = acc[4] * invd + bb.x; v[5] = acc[5] * invd + bb.y;
        v[6] = acc[6] * invd + bb.z; v[7] = acc[7] * invd + bb.w;
#pragma unroll
        for (int k = 0; k < 8; ++k) mk = fmaxf(mk, v[k]);
    }
    mk = fmaxf(mk, __shfl_xor(mk, 1, 64));
    mk = fmaxf(mk, __shfl_xor(mk, 2, 64));
    mk = fmaxf(mk, __shfl_xor(mk, 4, 64));
    float e = 0.f;
    if (act) {
#pragma unroll
        for (int k = 0; k < 8; ++k) e += __expf(v[k] - mk);
    }
    e += __shfl_xor(e, 1, 64);
    e += __shfl_xor(e, 2, 64);
    e += __shfl_xor(e, 4, 64);
    float lse = mk + logf(e);
    if (lane < 5) {   // group 0, active channel lanes
        float4 o0 = make_float4(v[0] - lse, v[1] - lse, v[2] - lse, v[3] - lse);
        float4 o1 = make_float4(v[4] - lse, v[5] - lse, v[6] - lse, v[7] - lse);
        float* po = out + (size_t)d * NC + cl * 8;
        *(float4*)po = o0;
        *(float4*)(po + 4) = o1;
    }
}

extern "C" void kernel_launch(void* const* d_in, const int* in_sizes, int n_in,
                              void* d_out, int out_size, void* d_ws, size_t ws_size,
                              hipStream_t stream) {
    const float* x       = (const float*)d_in[0];
    const unsigned* eidx = (const unsigned*)d_in[1];
    const float* W1      = (const float*)d_in[2];
    const float* atts1   = (const float*)d_in[3];
    const float* attd1   = (const float*)d_in[4];
    const float* b1      = (const float*)d_in[5];
    const float* W2      = (const float*)d_in[6];
    const float* atts2   = (const float*)d_in[7];
    const float* attd2   = (const float*)d_in[8];
    const float* b2      = (const float*)d_in[9];
    float* out = (float*)d_out;

    char* base = (char*)d_ws;
    size_t off = 0;
    auto takeB = [&](size_t bytes) {
        void* p = base + off;
        off = (off + bytes + 255) & ~(size_t)255;
        return p;
    };
    unsigned* flag = (unsigned*)takeB(256);
    int* cnt       = (int*)takeB((size_t)NODES * 4);
    int* fill      = (int*)takeB((size_t)NODES * 4);
    int* rowPtr    = (int*)takeB((size_t)(NODES + 1) * 4);
    int* csrSrc    = (int*)takeB((size_t)ETOT * 4 + 256);
    unsigned short* h1b  = (unsigned short*)takeB((size_t)NODES * F1 * 2);
    float* as1     = (float*)takeB((size_t)NODES * NHEAD * 4);
    float* ad1     = (float*)takeB((size_t)NODES * NHEAD * 4);
    unsigned short* out1b = (unsigned short*)takeB((size_t)NODES * F1 * 2);
    unsigned short* h2b  = (unsigned short*)takeB((size_t)NODES * NC * 2 + 256);
    float* as2     = (float*)takeB((size_t)NODES * 4);
    float* ad2     = (float*)takeB((size_t)NODES * 4);

    hipMemsetAsync(flag, 0, 4, stream);
    hipMemsetAsync(cnt, 0, (size_t)NODES * 4, stream);
    hipMemsetAsync(fill, 0, (size_t)NODES * 4, stream);

    detect_k<<<1, 256, 0, stream>>>(eidx, flag);

    // CSR build (by destination), reading edge_index directly
    hist_k<<<(ETOT + 255) / 256, 256, 0, stream>>>(eidx, flag, cnt);
    scan_k<<<1, 1024, 0, stream>>>(cnt, rowPtr);
    scatter_k<<<(ETOT + 255) / 256, 256, 0, stream>>>(eidx, flag, rowPtr, fill, csrSrc);

    // Layer 1
    gemm1<<<(NODES + 31) / 32, 256, 0, stream>>>(x, W1, atts1, attd1, h1b, as1, ad1);
    msg1<<<NODES / 4, 256, 0, stream>>>(rowPtr, csrSrc, as1, ad1, h1b, b1, out1b);

    // Layer 2
    gemm2k<<<NODES / 8, 320, 0, stream>>>(out1b, W2, atts2, attd2, h2b, as2, ad2);
    msg2<<<NODES / 4, 256, 0, stream>>>(rowPtr, csrSrc, as2, ad2, h2b, b2, out);
}

// Round 6
// 281.612 us; speedup vs baseline: 5.0195x; 1.2753x over previous
//
#include <hip/hip_runtime.h>
#include <math.h>

#define NODES 50000
#define NEDGE 800000
#define ETOT  (NEDGE + NODES)   // edges + self loops = 850000
#define NF    256
#define F1    128               // HEADS*NHID
#define NHEAD 8
#define NHID  16
#define NC    40
#define SCAN_BLK 196            // ceil((NODES+1)/256)

__device__ __forceinline__ float bflo(unsigned u) { return __uint_as_float(u << 16); }
__device__ __forceinline__ float bfhi(unsigned u) { return __uint_as_float(u & 0xffff0000u); }
__device__ __forceinline__ unsigned short f2bf(float f) {
    unsigned u = __float_as_uint(f);
    unsigned r = u + 0x7fffu + ((u >> 16) & 1u);   // RNE
    return (unsigned short)(r >> 16);
}
__device__ __forceinline__ unsigned pk2(float a, float b) {
    return (unsigned)f2bf(a) | ((unsigned)f2bf(b) << 16);
}

// ---------- edge index dtype detect ----------
__global__ void detect_k(const unsigned* __restrict__ u, unsigned* __restrict__ flag) {
    int t = threadIdx.x;              // 256 threads
    if (u[2 * t + 1] != 0u) atomicOr(flag, 1u);   // nonzero hi-word pattern => int32 data
}

// ---------- CSR build (reads edge_index directly) ----------
__global__ void hist_k(const unsigned* __restrict__ u, const unsigned* __restrict__ flag,
                       int* __restrict__ cnt) {
    int e = blockIdx.x * 256 + threadIdx.x;
    if (e >= ETOT) return;
    int d;
    if (e < NEDGE) d = (*flag) ? (int)u[NEDGE + e] : (int)u[2 * NEDGE + 2 * e];
    else d = e - NEDGE;
    atomicAdd(&cnt[d], 1);
}

// ---------- multi-block exclusive scan of cnt[0..NODES] -> rowPtr ----------
__global__ __launch_bounds__(256) void scanA(const int* __restrict__ cnt,
                                             int* __restrict__ rowPtr,
                                             int* __restrict__ blockSum) {
    int idx = blockIdx.x * 256 + threadIdx.x;
    int lane = threadIdx.x & 63, w = threadIdx.x >> 6;
    int v = (idx < NODES) ? cnt[idx] : 0;
    int s = v;
#pragma unroll
    for (int off = 1; off < 64; off <<= 1) {
        int o = __shfl_up(s, off, 64);
        if (lane >= off) s += o;
    }
    __shared__ int wsum[4];
    if (lane == 63) wsum[w] = s;
    __syncthreads();
    int wadd = 0;
    for (int i = 0; i < w; ++i) wadd += wsum[i];
    int incl = s + wadd;
    if (idx <= NODES) rowPtr[idx] = incl - v;        // block-local exclusive
    if (threadIdx.x == 255) blockSum[blockIdx.x] = incl;
}

__global__ __launch_bounds__(256) void scanB(const int* __restrict__ blockSum,
                                             int* __restrict__ blockOff) {
    __shared__ int sh[256];
    int t = threadIdx.x;
    int v = (t < SCAN_BLK) ? blockSum[t] : 0;
    sh[t] = v;
    __syncthreads();
    for (int off = 1; off < 256; off <<= 1) {
        int o = (t >= off) ? sh[t - off] : 0;
        __syncthreads();
        sh[t] += o;
        __syncthreads();
    }
    if (t < SCAN_BLK) blockOff[t] = sh[t] - v;       // exclusive
}

__global__ __launch_bounds__(256) void scanC(int* __restrict__ rowPtr,
                                             const int* __restrict__ blockOff) {
    int idx = blockIdx.x * 256 + threadIdx.x;
    if (idx <= NODES) rowPtr[idx] += blockOff[blockIdx.x];
}

__global__ void scatter_k(const unsigned* __restrict__ u, const unsigned* __restrict__ flag,
                          const int* __restrict__ rowPtr, int* __restrict__ fill,
                          int* __restrict__ csrSrc) {
    int e = blockIdx.x * 256 + threadIdx.x;
    if (e >= ETOT) return;
    int s, d;
    if (e < NEDGE) {
        if (*flag) { s = (int)u[e]; d = (int)u[NEDGE + e]; }
        else       { s = (int)u[2 * e]; d = (int)u[2 * NEDGE + 2 * e]; }
    } else s = d = e - NEDGE;
    int pos = rowPtr[d] + atomicAdd(&fill[d], 1);
    csrSrc[pos] = s;
}

// ---------- GEMM1: x[N,256] @ W1[256,128] -> h1b (bf16) + fused a1k ----------
__global__ __launch_bounds__(256) void gemm1(const float* __restrict__ x,
                                             const float* __restrict__ W,
                                             const float* __restrict__ atts1,
                                             const float* __restrict__ attd1,
                                             unsigned short* __restrict__ h1b,
                                             float* __restrict__ as1,
                                             float* __restrict__ ad1) {
    __shared__ float xs[32][NF];  // 32 KB
    int t = threadIdx.x;
    int base = blockIdx.x * 32;
#pragma unroll
    for (int r = 0; r < 8; ++r) {
        int idx = r * 256 + t;       // float4 index
        int row = idx >> 6;
        int c4 = idx & 63;
        int n = base + row;
        float4 v = make_float4(0.f, 0.f, 0.f, 0.f);
        if (n < NODES) v = ((const float4*)(x + (size_t)n * NF))[c4];
        ((float4*)(&xs[row][0]))[c4] = v;
    }
    __syncthreads();
    int tc = t & 31;   // column group: cols c0..c0+3
    int ng = t >> 5;   // node group 0..7 (4 nodes each)
    int c0 = tc * 4;
    float acc[4][4];
#pragma unroll
    for (int j = 0; j < 4; ++j)
#pragma unroll
        for (int i = 0; i < 4; ++i) acc[j][i] = 0.f;

    for (int k4 = 0; k4 < NF / 4; ++k4) {
        float4 xv[4];
#pragma unroll
        for (int j = 0; j < 4; ++j)
            xv[j] = *(const float4*)(&xs[ng * 4 + j][k4 * 4]);
        const float* wp = W + (size_t)k4 * 4 * F1 + c0;
#pragma unroll
        for (int dk = 0; dk < 4; ++dk) {
            float4 wv = *(const float4*)(wp + dk * F1);
#pragma unroll
            for (int j = 0; j < 4; ++j) {
                float xj = (dk == 0) ? xv[j].x : (dk == 1) ? xv[j].y : (dk == 2) ? xv[j].z : xv[j].w;
                acc[j][0] += xj * wv.x;
                acc[j][1] += xj * wv.y;
                acc[j][2] += xj * wv.z;
                acc[j][3] += xj * wv.w;
            }
        }
    }
#pragma unroll
    for (int j = 0; j < 4; ++j) {
        int n = base + ng * 4 + j;
        if (n < NODES) {
            ushort4 o;
            o.x = f2bf(acc[j][0]); o.y = f2bf(acc[j][1]);
            o.z = f2bf(acc[j][2]); o.w = f2bf(acc[j][3]);
            *(ushort4*)(h1b + (size_t)n * F1 + c0) = o;
        }
    }
    // fused a1k
    __syncthreads();
    float* shs = (float*)xs;    // [32 nodes][32 tc]
    float* shdd = shs + 1024;
    float4 wa = *(const float4*)(atts1 + c0);
    float4 wd = *(const float4*)(attd1 + c0);
#pragma unroll
    for (int j = 0; j < 4; ++j) {
        int nl = ng * 4 + j;
        shs[nl * 32 + tc]  = acc[j][0] * wa.x + acc[j][1] * wa.y + acc[j][2] * wa.z + acc[j][3] * wa.w;
        shdd[nl * 32 + tc] = acc[j][0] * wd.x + acc[j][1] * wd.y + acc[j][2] * wd.z + acc[j][3] * wd.w;
    }
    __syncthreads();
    int nl = t >> 3, h = t & 7, n = base + nl;
    if (n < NODES) {
        const float* ps = shs + nl * 32 + h * 4;
        const float* pd = shdd + nl * 32 + h * 4;
        as1[(size_t)n * NHEAD + h] = ps[0] + ps[1] + ps[2] + ps[3];
        ad1[(size_t)n * NHEAD + h] = pd[0] + pd[1] + pd[2] + pd[3];
    }
}

// no-max softmax step: 8 channels per lane
#define PROC8(AV, HV)                                    \
    {                                                    \
        float l = (AV) + adv;                            \
        l = l > 0.f ? l : 0.2f * l;                      \
        float p = __expf(l);                             \
        den += p;                                        \
        acc[0] += p * bflo(HV.x); acc[1] += p * bfhi(HV.x); \
        acc[2] += p * bflo(HV.y); acc[3] += p * bfhi(HV.y); \
        acc[4] += p * bflo(HV.z); acc[5] += p * bfhi(HV.z); \
        acc[6] += p * bflo(HV.w); acc[7] += p * bfhi(HV.w); \
    }

// ---------- L1 gather: wave per dst, 4 edges/step, 8ch/lane, bias+ELU -> bf16 ----------
__global__ __launch_bounds__(256) void msg1(const int* __restrict__ rowPtr,
                                            const int* __restrict__ csrSrc,
                                            const float* __restrict__ as1,
                                            const float* __restrict__ ad1,
                                            const unsigned short* __restrict__ h1b,
                                            const float* __restrict__ b1,
                                            unsigned short* __restrict__ out1b) {
    int t = threadIdx.x;
    int wid = t >> 6, lane = t & 63;
    int d = blockIdx.x * 4 + wid;        // grid exact (50000/4)
    int g = lane >> 4;                    // edge subgroup 0..3
    int cl = lane & 15;                   // channel lane: ch 8*cl..8*cl+7
    int h = cl >> 1;                      // head
    float adv = ad1[(size_t)d * NHEAD + h];
    int rs = rowPtr[d], re = rowPtr[d + 1];
    float den = 0.f;
    float acc[8];
#pragma unroll
    for (int k = 0; k < 8; ++k) acc[k] = 0.f;

#define LD1(J0, AV, HV)                                               \
    {                                                                 \
        int j = (J0) + g;                                             \
        bool val = j < re;                                            \
        int jj = val ? j : re - 1;                                    \
        int ss = csrSrc[jj];                                          \
        AV = val ? as1[(size_t)ss * NHEAD + h] : -1e30f;              \
        HV = *(const uint4*)(h1b + (size_t)ss * F1 + cl * 8);         \
    }

    float av0, av1; uint4 hv0, hv1;
    LD1(rs, av0, hv0);
    LD1(rs + 4, av1, hv1);
    for (int j0 = rs; j0 < re; j0 += 8) {
        float ta, tb; uint4 ha, hb;
        LD1(j0 + 8, ta, ha);
        LD1(j0 + 12, tb, hb);
        PROC8(av0, hv0);
        PROC8(av1, hv1);
        av0 = ta; hv0 = ha; av1 = tb; hv1 = hb;
    }
#undef LD1

    // reduce across the 4 edge-groups
#pragma unroll
    for (int k = 0; k < 8; ++k) {
        acc[k] += __shfl_xor(acc[k], 16, 64);
        acc[k] += __shfl_xor(acc[k], 32, 64);
    }
    den += __shfl_xor(den, 16, 64);
    den += __shfl_xor(den, 32, 64);
    float invd = 1.f / (den + 1e-16f);

    if (g == 0) {
        const float4* bp = (const float4*)(b1 + cl * 8);
        float4 ba = bp[0], bb = bp[1];
        float v[8];
        v[0] = acc[0] * invd + ba.x; v[1] = acc[1] * invd + ba.y;
        v[2] = acc[2] * invd + ba.z; v[3] = acc[3] * invd + ba.w;
        v[4] = acc[4] * invd + bb.x; v[5] = acc[5] * invd + bb.y;
        v[6] = acc[6] * invd + bb.z; v[7] = acc[7] * invd + bb.w;
#pragma unroll
        for (int k = 0; k < 8; ++k) v[k] = v[k] > 0.f ? v[k] : expm1f(v[k]);
        uint4 o;
        o.x = pk2(v[0], v[1]); o.y = pk2(v[2], v[3]);
        o.z = pk2(v[4], v[5]); o.w = pk2(v[6], v[7]);
        *(uint4*)(out1b + (size_t)d * F1 + cl * 8) = o;
    }
}

// ---------- GEMM2: out1b[N,128]bf16 @ W2[128,40] -> h2b (bf16) + fused a2k ----------
__global__ __launch_bounds__(320) void gemm2k(const unsigned short* __restrict__ a,
                                              const float* __restrict__ W,
                                              const float* __restrict__ atts2,
                                              const float* __restrict__ attd2,
                                              unsigned short* __restrict__ h2b,
                                              float* __restrict__ as2,
                                              float* __restrict__ ad2) {
    __shared__ float xs[8][132];
    __shared__ float red[2][320];
    int t = threadIdx.x;
    int base = blockIdx.x * 8;           // grid exact (50000/8)
    if (t < 256) {
        int row = t >> 5, q = t & 31;
        uint2 u = *(const uint2*)(a + (size_t)(base + row) * F1 + q * 4);
        float4 f;
        f.x = bflo(u.x); f.y = bfhi(u.x); f.z = bflo(u.y); f.w = bfhi(u.y);
        *(float4*)(&xs[row][q * 4]) = f;
    }
    __syncthreads();
    int n = t / 40, c = t % 40;
    float acc = 0.f;
    for (int k4 = 0; k4 < 32; ++k4) {
        float4 xv = *(const float4*)(&xs[n][k4 * 4]);
        const float* wp = W + (size_t)k4 * 4 * NC + c;
        acc += xv.x * wp[0];
        acc += xv.y * wp[NC];
        acc += xv.z * wp[2 * NC];
        acc += xv.w * wp[3 * NC];
    }
    int node = base + n;
    h2b[(size_t)node * NC + c] = f2bf(acc);
    red[0][n * 40 + c] = acc * atts2[c];
    red[1][n * 40 + c] = acc * attd2[c];
    __syncthreads();
    if (t < 16) {
        int which = t >> 3, nn = t & 7;
        const float* p = red[which] + nn * 40;
        float s = 0.f;
        for (int q = 0; q < 40; ++q) s += p[q];
        if (which) ad2[base + nn] = s; else as2[base + nn] = s;
    }
}

// ---------- L2 gather: wave per dst, 8 edges/step, bias + log_softmax ----------
__global__ __launch_bounds__(256) void msg2(const int* __restrict__ rowPtr,
                                            const int* __restrict__ csrSrc,
                                            const float* __restrict__ as2,
                                            const float* __restrict__ ad2,
                                            const unsigned short* __restrict__ h2b,
                                            const float* __restrict__ b2,
                                            float* __restrict__ out) {
    int t = threadIdx.x;
    int wid = t >> 6, lane = t & 63;
    int d = blockIdx.x * 4 + wid;        // grid exact
    int g = lane >> 3;                    // edge subgroup 0..7
    int cl = lane & 7;                    // channel lane; active cl<5 (8 ch each)
    int clc = cl < 5 ? cl : 4;
    bool act = cl < 5;
    float adv = ad2[d];
    int rs = rowPtr[d], re = rowPtr[d + 1];
    float den = 0.f;
    float acc[8];
#pragma unroll
    for (int k = 0; k < 8; ++k) acc[k] = 0.f;

#define LD2(J0, AV, HV)                                               \
    {                                                                 \
        int j = (J0) + g;                                             \
        bool val = j < re;                                            \
        int jj = val ? j : re - 1;                                    \
        int ss = csrSrc[jj];                                          \
        AV = val ? as2[ss] : -1e30f;                                  \
        HV = *(const uint4*)(h2b + (size_t)ss * NC + clc * 8);        \
    }

    float av0, av1; uint4 hv0, hv1;
    LD2(rs, av0, hv0);
    LD2(rs + 8, av1, hv1);
    for (int j0 = rs; j0 < re; j0 += 16) {
        float ta, tb; uint4 ha, hb;
        LD2(j0 + 16, ta, ha);
        LD2(j0 + 24, tb, hb);
        PROC8(av0, hv0);
        PROC8(av1, hv1);
        av0 = ta; hv0 = ha; av1 = tb; hv1 = hb;
    }
#undef LD2

    // reduce across the 8 edge-groups
#pragma unroll
    for (int k = 0; k < 8; ++k) {
        acc[k] += __shfl_xor(acc[k], 8, 64);
        acc[k] += __shfl_xor(acc[k], 16, 64);
        acc[k] += __shfl_xor(acc[k], 32, 64);
    }
    den += __shfl_xor(den, 8, 64);
    den += __shfl_xor(den, 16, 64);
    den += __shfl_xor(den, 32, 64);
    float invd = 1.f / (den + 1e-16f);

    float v[8];
    float mk = -1e30f;
    if (act) {
        const float4* bp = (const float4*)(b2 + cl * 8);
        float4 ba = bp[0], bb = bp[1];
        v[0] = acc[0] * invd + ba.x; v[1] = acc[1] * invd + ba.y;
        v[2] = acc[2] * invd + ba.z; v[3] = acc[3] * invd + ba.w;
        v[4] = acc[4] * invd + bb.x; v[5] = acc[5] * invd + bb.y;
        v[6] = acc[6] * invd + bb.z; v[7] = acc[7] * invd + bb.w;
#pragma unroll
        for (int k = 0; k < 8; ++k) mk = fmaxf(mk, v[k]);
    }
    mk = fmaxf(mk, __shfl_xor(mk, 1, 64));
    mk = fmaxf(mk, __shfl_xor(mk, 2, 64));
    mk = fmaxf(mk, __shfl_xor(mk, 4, 64));
    float e = 0.f;
    if (act) {
#pragma unroll
        for (int k = 0; k < 8; ++k) e += __expf(v[k] - mk);
    }
    e += __shfl_xor(e, 1, 64);
    e += __shfl_xor(e, 2, 64);
    e += __shfl_xor(e, 4, 64);
    float lse = mk + logf(e);
    if (lane < 5) {   // group 0, active channel lanes
        float4 o0 = make_float4(v[0] - lse, v[1] - lse, v[2] - lse, v[3] - lse);
        float4 o1 = make_float4(v[4] - lse, v[5] - lse, v[6] - lse, v[7] - lse);
        float* po = out + (size_t)d * NC + cl * 8;
        *(float4*)po = o0;
        *(float4*)(po + 4) = o1;
    }
}

extern "C" void kernel_launch(void* const* d_in, const int* in_sizes, int n_in,
                              void* d_out, int out_size, void* d_ws, size_t ws_size,
                              hipStream_t stream) {
    const float* x       = (const float*)d_in[0];
    const unsigned* eidx = (const unsigned*)d_in[1];
    const float* W1      = (const float*)d_in[2];
    const float* atts1   = (const float*)d_in[3];
    const float* attd1   = (const float*)d_in[4];
    const float* b1      = (const float*)d_in[5];
    const float* W2      = (const float*)d_in[6];
    const float* atts2   = (const float*)d_in[7];
    const float* attd2   = (const float*)d_in[8];
    const float* b2      = (const float*)d_in[9];
    float* out = (float*)d_out;

    char* base = (char*)d_ws;
    size_t off = 0;
    auto takeB = [&](size_t bytes) {
        void* p = base + off;
        off = (off + bytes + 255) & ~(size_t)255;
        return p;
    };
    unsigned* flag = (unsigned*)takeB(256);
    int* cnt       = (int*)takeB((size_t)NODES * 4);
    int* fill      = (int*)takeB((size_t)NODES * 4);
    int* rowPtr    = (int*)takeB((size_t)(NODES + 1) * 4);
    int* blockSum  = (int*)takeB(SCAN_BLK * 4);
    int* blockOff  = (int*)takeB(SCAN_BLK * 4);
    int* csrSrc    = (int*)takeB((size_t)ETOT * 4 + 256);
    unsigned short* h1b  = (unsigned short*)takeB((size_t)NODES * F1 * 2);
    float* as1     = (float*)takeB((size_t)NODES * NHEAD * 4);
    float* ad1     = (float*)takeB((size_t)NODES * NHEAD * 4);
    unsigned short* out1b = (unsigned short*)takeB((size_t)NODES * F1 * 2);
    unsigned short* h2b  = (unsigned short*)takeB((size_t)NODES * NC * 2 + 256);
    float* as2     = (float*)takeB((size_t)NODES * 4);
    float* ad2     = (float*)takeB((size_t)NODES * 4);

    hipMemsetAsync(flag, 0, 4, stream);
    hipMemsetAsync(cnt, 0, (size_t)NODES * 4, stream);
    hipMemsetAsync(fill, 0, (size_t)NODES * 4, stream);

    detect_k<<<1, 256, 0, stream>>>(eidx, flag);

    // CSR build (by destination), reading edge_index directly
    hist_k<<<(ETOT + 255) / 256, 256, 0, stream>>>(eidx, flag, cnt);
    scanA<<<SCAN_BLK, 256, 0, stream>>>(cnt, rowPtr, blockSum);
    scanB<<<1, 256, 0, stream>>>(blockSum, blockOff);
    scanC<<<SCAN_BLK, 256, 0, stream>>>(rowPtr, blockOff);
    scatter_k<<<(ETOT + 255) / 256, 256, 0, stream>>>(eidx, flag, rowPtr, fill, csrSrc);

    // Layer 1
    gemm1<<<(NODES + 31) / 32, 256, 0, stream>>>(x, W1, atts1, attd1, h1b, as1, ad1);
    msg1<<<NODES / 4, 256, 0, stream>>>(rowPtr, csrSrc, as1, ad1, h1b, b1, out1b);

    // Layer 2
    gemm2k<<<NODES / 8, 320, 0, stream>>>(out1b, W2, atts2, attd2, h2b, as2, ad2);
    msg2<<<NODES / 4, 256, 0, stream>>>(rowPtr, csrSrc, as2, ad2, h2b, b2, out);
}

// Round 7
// 258.351 us; speedup vs baseline: 5.4715x; 1.0900x over previous
//
#include <hip/hip_runtime.h>
#include <math.h>

#define NODES 50000
#define NEDGE 800000
#define ETOT  (NEDGE + NODES)   // edges + self loops = 850000
#define NF    256
#define F1    128               // HEADS*NHID
#define NHEAD 8
#define NHID  16
#define NC    40
#define SCAN_BLK 196            // ceil((NODES+1)/256)

typedef __attribute__((ext_vector_type(8))) short bf16x8;
typedef __attribute__((ext_vector_type(4))) float f32x4;

__device__ __forceinline__ float bflo(unsigned u) { return __uint_as_float(u << 16); }
__device__ __forceinline__ float bfhi(unsigned u) { return __uint_as_float(u & 0xffff0000u); }
__device__ __forceinline__ unsigned short f2bf(float f) {
    unsigned u = __float_as_uint(f);
    unsigned r = u + 0x7fffu + ((u >> 16) & 1u);   // RNE
    return (unsigned short)(r >> 16);
}
__device__ __forceinline__ unsigned pk2(float a, float b) {
    return (unsigned)f2bf(a) | ((unsigned)f2bf(b) << 16);
}

// ---------- edge index dtype detect ----------
__global__ void detect_k(const unsigned* __restrict__ u, unsigned* __restrict__ flag) {
    int t = threadIdx.x;              // 256 threads
    if (u[2 * t + 1] != 0u) atomicOr(flag, 1u);   // nonzero hi-word pattern => int32 data
}

// ---------- CSR build (reads edge_index directly) ----------
__global__ void hist_k(const unsigned* __restrict__ u, const unsigned* __restrict__ flag,
                       int* __restrict__ cnt) {
    int e = blockIdx.x * 256 + threadIdx.x;
    if (e >= ETOT) return;
    int d;
    if (e < NEDGE) d = (*flag) ? (int)u[NEDGE + e] : (int)u[2 * NEDGE + 2 * e];
    else d = e - NEDGE;
    atomicAdd(&cnt[d], 1);
}

// ---------- multi-block exclusive scan of cnt[0..NODES] -> rowPtr ----------
__global__ __launch_bounds__(256) void scanA(const int* __restrict__ cnt,
                                             int* __restrict__ rowPtr,
                                             int* __restrict__ blockSum) {
    int idx = blockIdx.x * 256 + threadIdx.x;
    int lane = threadIdx.x & 63, w = threadIdx.x >> 6;
    int v = (idx < NODES) ? cnt[idx] : 0;
    int s = v;
#pragma unroll
    for (int off = 1; off < 64; off <<= 1) {
        int o = __shfl_up(s, off, 64);
        if (lane >= off) s += o;
    }
    __shared__ int wsum[4];
    if (lane == 63) wsum[w] = s;
    __syncthreads();
    int wadd = 0;
    for (int i = 0; i < w; ++i) wadd += wsum[i];
    int incl = s + wadd;
    if (idx <= NODES) rowPtr[idx] = incl - v;        // block-local exclusive
    if (threadIdx.x == 255) blockSum[blockIdx.x] = incl;
}

__global__ __launch_bounds__(256) void scanB(const int* __restrict__ blockSum,
                                             int* __restrict__ blockOff) {
    __shared__ int sh[256];
    int t = threadIdx.x;
    int v = (t < SCAN_BLK) ? blockSum[t] : 0;
    sh[t] = v;
    __syncthreads();
    for (int off = 1; off < 256; off <<= 1) {
        int o = (t >= off) ? sh[t - off] : 0;
        __syncthreads();
        sh[t] += o;
        __syncthreads();
    }
    if (t < SCAN_BLK) blockOff[t] = sh[t] - v;       // exclusive
}

__global__ __launch_bounds__(256) void scanC(int* __restrict__ rowPtr,
                                             const int* __restrict__ blockOff) {
    int idx = blockIdx.x * 256 + threadIdx.x;
    if (idx <= NODES) rowPtr[idx] += blockOff[blockIdx.x];
}

__global__ void scatter_k(const unsigned* __restrict__ u, const unsigned* __restrict__ flag,
                          const int* __restrict__ rowPtr, int* __restrict__ fill,
                          int* __restrict__ csrSrc) {
    int e = blockIdx.x * 256 + threadIdx.x;
    if (e >= ETOT) return;
    int s, d;
    if (e < NEDGE) {
        if (*flag) { s = (int)u[e]; d = (int)u[NEDGE + e]; }
        else       { s = (int)u[2 * e]; d = (int)u[2 * NEDGE + 2 * e]; }
    } else s = d = e - NEDGE;
    int pos = rowPtr[d] + atomicAdd(&fill[d], 1);
    csrSrc[pos] = s;
}

// ---------- prep: W1t144[144][256] bf16 = [W1^T ; W1.atts1 per head ; W1.attd1] ----------
__global__ void prepW1(const float* __restrict__ W1, const float* __restrict__ atts1,
                       const float* __restrict__ attd1, unsigned short* __restrict__ W1t) {
    int n = blockIdx.x;      // 0..143
    int k = threadIdx.x;     // 0..255
    float v;
    if (n < 128) {
        v = W1[(size_t)k * F1 + n];
    } else if (n < 136) {
        int h = n - 128; v = 0.f;
#pragma unroll
        for (int c = 0; c < 16; ++c) v += W1[(size_t)k * F1 + h * 16 + c] * atts1[h * 16 + c];
    } else {
        int h = n - 136; v = 0.f;
#pragma unroll
        for (int c = 0; c < 16; ++c) v += W1[(size_t)k * F1 + h * 16 + c] * attd1[h * 16 + c];
    }
    W1t[(size_t)n * NF + k] = f2bf(v);
}

// ---------- MFMA GEMM1: x[N,256] @ W1t144^T -> h1b[,128] bf16 + as1/ad1 ----------
__global__ __launch_bounds__(256) void gemm1m(const float* __restrict__ x,
                                              const unsigned short* __restrict__ W1t,
                                              unsigned short* __restrict__ h1b,
                                              float* __restrict__ as1,
                                              float* __restrict__ ad1) {
    int t = threadIdx.x;
    int wave = t >> 6, lane = t & 63;
    int mbase = blockIdx.x * 64 + wave * 16;
    int row = mbase + (lane & 15);
    int rowc = min(row, NODES - 1);
    int kg = lane >> 4;              // 0..3
    const float* xr = x + (size_t)rowc * NF + kg * 8;

    f32x4 acc[9];
#pragma unroll
    for (int f = 0; f < 9; ++f) acc[f] = (f32x4){0.f, 0.f, 0.f, 0.f};

    const unsigned short* wb = W1t + (size_t)(lane & 15) * NF + kg * 8;

    float4 a0 = *(const float4*)(xr);
    float4 a1 = *(const float4*)(xr + 4);
    for (int ks = 0; ks < 8; ++ks) {
        float4 n0 = make_float4(0.f, 0.f, 0.f, 0.f), n1 = n0;
        if (ks < 7) {
            n0 = *(const float4*)(xr + 32 * (ks + 1));
            n1 = *(const float4*)(xr + 32 * (ks + 1) + 4);
        }
        union { uint4 u; bf16x8 v; } A;
        A.u.x = pk2(a0.x, a0.y); A.u.y = pk2(a0.z, a0.w);
        A.u.z = pk2(a1.x, a1.y); A.u.w = pk2(a1.z, a1.w);
        const unsigned short* wk = wb + ks * 32;
#pragma unroll
        for (int f = 0; f < 9; ++f) {
            union { uint4 u; bf16x8 v; } B;
            B.u = *(const uint4*)(wk + (size_t)f * 16 * NF);
            acc[f] = __builtin_amdgcn_mfma_f32_16x16x32_bf16(A.v, B.v, acc[f], 0, 0, 0);
        }
        a0 = n0; a1 = n1;
    }

    // store: C/D layout col=lane&15, row=(lane>>4)*4+reg
    int col = lane & 15;
    int rbase = mbase + (lane >> 4) * 4;
#pragma unroll
    for (int f = 0; f < 8; ++f) {
#pragma unroll
        for (int i = 0; i < 4; ++i) {
            int r = rbase + i;
            if (r < NODES) h1b[(size_t)r * F1 + f * 16 + col] = f2bf(acc[f][i]);
        }
    }
#pragma unroll
    for (int i = 0; i < 4; ++i) {
        int r = rbase + i;
        if (r < NODES) {
            float v = acc[8][i];
            if (col < 8) as1[(size_t)r * NHEAD + col] = v;
            else ad1[(size_t)r * NHEAD + (col - 8)] = v;
        }
    }
}

// no-max softmax step: 8 channels per lane
#define PROC8(AV, HV)                                    \
    {                                                    \
        float l = (AV) + adv;                            \
        l = l > 0.f ? l : 0.2f * l;                      \
        float p = __expf(l);                             \
        den += p;                                        \
        acc[0] += p * bflo(HV.x); acc[1] += p * bfhi(HV.x); \
        acc[2] += p * bflo(HV.y); acc[3] += p * bfhi(HV.y); \
        acc[4] += p * bflo(HV.z); acc[5] += p * bfhi(HV.z); \
        acc[6] += p * bflo(HV.w); acc[7] += p * bfhi(HV.w); \
    }

// ---------- L1 gather: wave per dst, 4 edges/step, 8ch/lane, bias+ELU -> bf16 ----------
__global__ __launch_bounds__(256) void msg1(const int* __restrict__ rowPtr,
                                            const int* __restrict__ csrSrc,
                                            const float* __restrict__ as1,
                                            const float* __restrict__ ad1,
                                            const unsigned short* __restrict__ h1b,
                                            const float* __restrict__ b1,
                                            unsigned short* __restrict__ out1b) {
    int t = threadIdx.x;
    int wid = t >> 6, lane = t & 63;
    int d = blockIdx.x * 4 + wid;        // grid exact (50000/4)
    int g = lane >> 4;                    // edge subgroup 0..3
    int cl = lane & 15;                   // channel lane: ch 8*cl..8*cl+7
    int h = cl >> 1;                      // head
    float adv = ad1[(size_t)d * NHEAD + h];
    int rs = rowPtr[d], re = rowPtr[d + 1];
    float den = 0.f;
    float acc[8];
#pragma unroll
    for (int k = 0; k < 8; ++k) acc[k] = 0.f;

#define LD1(J0, AV, HV)                                               \
    {                                                                 \
        int j = (J0) + g;                                             \
        bool val = j < re;                                            \
        int jj = val ? j : re - 1;                                    \
        int ss = csrSrc[jj];                                          \
        AV = val ? as1[(size_t)ss * NHEAD + h] : -1e30f;              \
        HV = *(const uint4*)(h1b + (size_t)ss * F1 + cl * 8);         \
    }

    float av0, av1; uint4 hv0, hv1;
    LD1(rs, av0, hv0);
    LD1(rs + 4, av1, hv1);
    for (int j0 = rs; j0 < re; j0 += 8) {
        float ta, tb; uint4 ha, hb;
        LD1(j0 + 8, ta, ha);
        LD1(j0 + 12, tb, hb);
        PROC8(av0, hv0);
        PROC8(av1, hv1);
        av0 = ta; hv0 = ha; av1 = tb; hv1 = hb;
    }
#undef LD1

    // reduce across the 4 edge-groups
#pragma unroll
    for (int k = 0; k < 8; ++k) {
        acc[k] += __shfl_xor(acc[k], 16, 64);
        acc[k] += __shfl_xor(acc[k], 32, 64);
    }
    den += __shfl_xor(den, 16, 64);
    den += __shfl_xor(den, 32, 64);
    float invd = 1.f / (den + 1e-16f);

    if (g == 0) {
        const float4* bp = (const float4*)(b1 + cl * 8);
        float4 ba = bp[0], bb = bp[1];
        float v[8];
        v[0] = acc[0] * invd + ba.x; v[1] = acc[1] * invd + ba.y;
        v[2] = acc[2] * invd + ba.z; v[3] = acc[3] * invd + ba.w;
        v[4] = acc[4] * invd + bb.x; v[5] = acc[5] * invd + bb.y;
        v[6] = acc[6] * invd + bb.z; v[7] = acc[7] * invd + bb.w;
#pragma unroll
        for (int k = 0; k < 8; ++k) v[k] = v[k] > 0.f ? v[k] : expm1f(v[k]);
        uint4 o;
        o.x = pk2(v[0], v[1]); o.y = pk2(v[2], v[3]);
        o.z = pk2(v[4], v[5]); o.w = pk2(v[6], v[7]);
        *(uint4*)(out1b + (size_t)d * F1 + cl * 8) = o;
    }
}

// ---------- GEMM2: out1b[N,128]bf16 @ W2[128,40] -> h2b (bf16) + fused a2k ----------
__global__ __launch_bounds__(320) void gemm2k(const unsigned short* __restrict__ a,
                                              const float* __restrict__ W,
                                              const float* __restrict__ atts2,
                                              const float* __restrict__ attd2,
                                              unsigned short* __restrict__ h2b,
                                              float* __restrict__ as2,
                                              float* __restrict__ ad2) {
    __shared__ float xs[8][132];
    __shared__ float red[2][320];
    int t = threadIdx.x;
    int base = blockIdx.x * 8;           // grid exact (50000/8)
    if (t < 256) {
        int row = t >> 5, q = t & 31;
        uint2 u = *(const uint2*)(a + (size_t)(base + row) * F1 + q * 4);
        float4 f;
        f.x = bflo(u.x); f.y = bfhi(u.x); f.z = bflo(u.y); f.w = bfhi(u.y);
        *(float4*)(&xs[row][q * 4]) = f;
    }
    __syncthreads();
    int n = t / 40, c = t % 40;
    float acc = 0.f;
    for (int k4 = 0; k4 < 32; ++k4) {
        float4 xv = *(const float4*)(&xs[n][k4 * 4]);
        const float* wp = W + (size_t)k4 * 4 * NC + c;
        acc += xv.x * wp[0];
        acc += xv.y * wp[NC];
        acc += xv.z * wp[2 * NC];
        acc += xv.w * wp[3 * NC];
    }
    int node = base + n;
    h2b[(size_t)node * NC + c] = f2bf(acc);
    red[0][n * 40 + c] = acc * atts2[c];
    red[1][n * 40 + c] = acc * attd2[c];
    __syncthreads();
    if (t < 16) {
        int which = t >> 3, nn = t & 7;
        const float* p = red[which] + nn * 40;
        float s = 0.f;
        for (int q = 0; q < 40; ++q) s += p[q];
        if (which) ad2[base + nn] = s; else as2[base + nn] = s;
    }
}

// ---------- L2 gather: wave per dst, 8 edges/step, bias + log_softmax ----------
__global__ __launch_bounds__(256) void msg2(const int* __restrict__ rowPtr,
                                            const int* __restrict__ csrSrc,
                                            const float* __restrict__ as2,
                                            const float* __restrict__ ad2,
                                            const unsigned short* __restrict__ h2b,
                                            const float* __restrict__ b2,
                                            float* __restrict__ out) {
    int t = threadIdx.x;
    int wid = t >> 6, lane = t & 63;
    int d = blockIdx.x * 4 + wid;        // grid exact
    int g = lane >> 3;                    // edge subgroup 0..7
    int cl = lane & 7;                    // channel lane; active cl<5 (8 ch each)
    int clc = cl < 5 ? cl : 4;
    bool act = cl < 5;
    float adv = ad2[d];
    int rs = rowPtr[d], re = rowPtr[d + 1];
    float den = 0.f;
    float acc[8];
#pragma unroll
    for (int k = 0; k < 8; ++k) acc[k] = 0.f;

#define LD2(J0, AV, HV)                                               \
    {                                                                 \
        int j = (J0) + g;                                             \
        bool val = j < re;                                            \
        int jj = val ? j : re - 1;                                    \
        int ss = csrSrc[jj];                                          \
        AV = val ? as2[ss] : -1e30f;                                  \
        HV = *(const uint4*)(h2b + (size_t)ss * NC + clc * 8);        \
    }

    float av0, av1; uint4 hv0, hv1;
    LD2(rs, av0, hv0);
    LD2(rs + 8, av1, hv1);
    for (int j0 = rs; j0 < re; j0 += 16) {
        float ta, tb; uint4 ha, hb;
        LD2(j0 + 16, ta, ha);
        LD2(j0 + 24, tb, hb);
        PROC8(av0, hv0);
        PROC8(av1, hv1);
        av0 = ta; hv0 = ha; av1 = tb; hv1 = hb;
    }
#undef LD2

    // reduce across the 8 edge-groups
#pragma unroll
    for (int k = 0; k < 8; ++k) {
        acc[k] += __shfl_xor(acc[k], 8, 64);
        acc[k] += __shfl_xor(acc[k], 16, 64);
        acc[k] += __shfl_xor(acc[k], 32, 64);
    }
    den += __shfl_xor(den, 8, 64);
    den += __shfl_xor(den, 16, 64);
    den += __shfl_xor(den, 32, 64);
    float invd = 1.f / (den + 1e-16f);

    float v[8];
    float mk = -1e30f;
    if (act) {
        const float4* bp = (const float4*)(b2 + cl * 8);
        float4 ba = bp[0], bb = bp[1];
        v[0] = acc[0] * invd + ba.x; v[1] = acc[1] * invd + ba.y;
        v[2] = acc[2] * invd + ba.z; v[3] = acc[3] * invd + ba.w;
        v[4] = acc[4] * invd + bb.x; v[5] = acc[5] * invd + bb.y;
        v[6] = acc[6] * invd + bb.z; v[7] = acc[7] * invd + bb.w;
#pragma unroll
        for (int k = 0; k < 8; ++k) mk = fmaxf(mk, v[k]);
    }
    mk = fmaxf(mk, __shfl_xor(mk, 1, 64));
    mk = fmaxf(mk, __shfl_xor(mk, 2, 64));
    mk = fmaxf(mk, __shfl_xor(mk, 4, 64));
    float e = 0.f;
    if (act) {
#pragma unroll
        for (int k = 0; k < 8; ++k) e += __expf(v[k] - mk);
    }
    e += __shfl_xor(e, 1, 64);
    e += __shfl_xor(e, 2, 64);
    e += __shfl_xor(e, 4, 64);
    float lse = mk + logf(e);
    if (lane < 5) {   // group 0, active channel lanes
        float4 o0 = make_float4(v[0] - lse, v[1] - lse, v[2] - lse, v[3] - lse);
        float4 o1 = make_float4(v[4] - lse, v[5] - lse, v[6] - lse, v[7] - lse);
        float* po = out + (size_t)d * NC + cl * 8;
        *(float4*)po = o0;
        *(float4*)(po + 4) = o1;
    }
}

extern "C" void kernel_launch(void* const* d_in, const int* in_sizes, int n_in,
                              void* d_out, int out_size, void* d_ws, size_t ws_size,
                              hipStream_t stream) {
    const float* x       = (const float*)d_in[0];
    const unsigned* eidx = (const unsigned*)d_in[1];
    const float* W1      = (const float*)d_in[2];
    const float* atts1   = (const float*)d_in[3];
    const float* attd1   = (const float*)d_in[4];
    const float* b1      = (const float*)d_in[5];
    const float* W2      = (const float*)d_in[6];
    const float* atts2   = (const float*)d_in[7];
    const float* attd2   = (const float*)d_in[8];
    const float* b2      = (const float*)d_in[9];
    float* out = (float*)d_out;

    char* base = (char*)d_ws;
    size_t off = 0;
    auto takeB = [&](size_t bytes) {
        void* p = base + off;
        off = (off + bytes + 255) & ~(size_t)255;
        return p;
    };
    unsigned* flag = (unsigned*)takeB(256);
    int* cnt       = (int*)takeB((size_t)NODES * 4);
    int* fill      = (int*)takeB((size_t)NODES * 4);
    int* rowPtr    = (int*)takeB((size_t)(NODES + 1) * 4);
    int* blockSum  = (int*)takeB(SCAN_BLK * 4);
    int* blockOff  = (int*)takeB(SCAN_BLK * 4);
    int* csrSrc    = (int*)takeB((size_t)ETOT * 4 + 256);
    unsigned short* W1t  = (unsigned short*)takeB((size_t)144 * NF * 2);
    unsigned short* h1b  = (unsigned short*)takeB((size_t)NODES * F1 * 2);
    float* as1     = (float*)takeB((size_t)NODES * NHEAD * 4);
    float* ad1     = (float*)takeB((size_t)NODES * NHEAD * 4);
    unsigned short* out1b = (unsigned short*)takeB((size_t)NODES * F1 * 2);
    unsigned short* h2b  = (unsigned short*)takeB((size_t)NODES * NC * 2 + 256);
    float* as2     = (float*)takeB((size_t)NODES * 4);
    float* ad2     = (float*)takeB((size_t)NODES * 4);

    hipMemsetAsync(flag, 0, 4, stream);
    hipMemsetAsync(cnt, 0, (size_t)NODES * 4, stream);
    hipMemsetAsync(fill, 0, (size_t)NODES * 4, stream);

    detect_k<<<1, 256, 0, stream>>>(eidx, flag);

    // CSR build (by destination), reading edge_index directly
    hist_k<<<(ETOT + 255) / 256, 256, 0, stream>>>(eidx, flag, cnt);
    scanA<<<SCAN_BLK, 256, 0, stream>>>(cnt, rowPtr, blockSum);
    scanB<<<1, 256, 0, stream>>>(blockSum, blockOff);
    scanC<<<SCAN_BLK, 256, 0, stream>>>(rowPtr, blockOff);
    scatter_k<<<(ETOT + 255) / 256, 256, 0, stream>>>(eidx, flag, rowPtr, fill, csrSrc);

    // Layer 1 (MFMA GEMM with fused a1k columns)
    prepW1<<<144, 256, 0, stream>>>(W1, atts1, attd1, W1t);
    gemm1m<<<(NODES + 63) / 64, 256, 0, stream>>>(x, W1t, h1b, as1, ad1);
    msg1<<<NODES / 4, 256, 0, stream>>>(rowPtr, csrSrc, as1, ad1, h1b, b1, out1b);

    // Layer 2
    gemm2k<<<NODES / 8, 320, 0, stream>>>(out1b, W2, atts2, attd2, h2b, as2, ad2);
    msg2<<<NODES / 4, 256, 0, stream>>>(rowPtr, csrSrc, as2, ad2, h2b, b2, out);
}

// Round 8
// 258.272 us; speedup vs baseline: 5.4731x; 1.0003x over previous
//
#include <hip/hip_runtime.h>
#include <math.h>

#define NODES 50000
#define NEDGE 800000
#define ETOT  (NEDGE + NODES)   // edges + self loops = 850000
#define NF    256
#define F1    128               // HEADS*NHID
#define NHEAD 8
#define NHID  16
#define NC    40
#define SCAN_BLK 196            // ceil((NODES+1)/256)

typedef __attribute__((ext_vector_type(8))) short bf16x8;
typedef __attribute__((ext_vector_type(4))) float f32x4;

__device__ __forceinline__ float bflo(unsigned u) { return __uint_as_float(u << 16); }
__device__ __forceinline__ float bfhi(unsigned u) { return __uint_as_float(u & 0xffff0000u); }
__device__ __forceinline__ unsigned short f2bf(float f) {
    unsigned u = __float_as_uint(f);
    unsigned r = u + 0x7fffu + ((u >> 16) & 1u);   // RNE
    return (unsigned short)(r >> 16);
}
__device__ __forceinline__ unsigned pk2(float a, float b) {
    return (unsigned)f2bf(a) | ((unsigned)f2bf(b) << 16);
}

// ---------- edge index dtype detect ----------
__global__ void detect_k(const unsigned* __restrict__ u, unsigned* __restrict__ flag) {
    int t = threadIdx.x;              // 256 threads
    if (u[2 * t + 1] != 0u) atomicOr(flag, 1u);   // nonzero hi-word pattern => int32 data
}

// ---------- CSR build (reads edge_index directly) ----------
__global__ void hist_k(const unsigned* __restrict__ u, const unsigned* __restrict__ flag,
                       int* __restrict__ cnt) {
    int e = blockIdx.x * 256 + threadIdx.x;
    if (e >= ETOT) return;
    int d;
    if (e < NEDGE) d = (*flag) ? (int)u[NEDGE + e] : (int)u[2 * NEDGE + 2 * e];
    else d = e - NEDGE;
    atomicAdd(&cnt[d], 1);
}

// ---------- multi-block exclusive scan of cnt[0..NODES] -> rowPtr ----------
__global__ __launch_bounds__(256) void scanA(const int* __restrict__ cnt,
                                             int* __restrict__ rowPtr,
                                             int* __restrict__ blockSum) {
    int idx = blockIdx.x * 256 + threadIdx.x;
    int lane = threadIdx.x & 63, w = threadIdx.x >> 6;
    int v = (idx < NODES) ? cnt[idx] : 0;
    int s = v;
#pragma unroll
    for (int off = 1; off < 64; off <<= 1) {
        int o = __shfl_up(s, off, 64);
        if (lane >= off) s += o;
    }
    __shared__ int wsum[4];
    if (lane == 63) wsum[w] = s;
    __syncthreads();
    int wadd = 0;
    for (int i = 0; i < w; ++i) wadd += wsum[i];
    int incl = s + wadd;
    if (idx <= NODES) rowPtr[idx] = incl - v;        // block-local exclusive
    if (threadIdx.x == 255) blockSum[blockIdx.x] = incl;
}

__global__ __launch_bounds__(256) void scanB(const int* __restrict__ blockSum,
                                             int* __restrict__ blockOff) {
    __shared__ int sh[256];
    int t = threadIdx.x;
    int v = (t < SCAN_BLK) ? blockSum[t] : 0;
    sh[t] = v;
    __syncthreads();
    for (int off = 1; off < 256; off <<= 1) {
        int o = (t >= off) ? sh[t - off] : 0;
        __syncthreads();
        sh[t] += o;
        __syncthreads();
    }
    if (t < SCAN_BLK) blockOff[t] = sh[t] - v;       // exclusive
}

__global__ __launch_bounds__(256) void scanC(int* __restrict__ rowPtr,
                                             const int* __restrict__ blockOff) {
    int idx = blockIdx.x * 256 + threadIdx.x;
    if (idx <= NODES) rowPtr[idx] += blockOff[blockIdx.x];
}

__global__ void scatter_k(const unsigned* __restrict__ u, const unsigned* __restrict__ flag,
                          const int* __restrict__ rowPtr, int* __restrict__ fill,
                          int* __restrict__ csrSrc) {
    int e = blockIdx.x * 256 + threadIdx.x;
    if (e >= ETOT) return;
    int s, d;
    if (e < NEDGE) {
        if (*flag) { s = (int)u[e]; d = (int)u[NEDGE + e]; }
        else       { s = (int)u[2 * e]; d = (int)u[2 * NEDGE + 2 * e]; }
    } else s = d = e - NEDGE;
    int pos = rowPtr[d] + atomicAdd(&fill[d], 1);
    csrSrc[pos] = s;
}

// ---------- prep: W1t144[144][256] bf16 = [W1^T ; W1.atts1 per head ; W1.attd1] ----------
__global__ void prepW1(const float* __restrict__ W1, const float* __restrict__ atts1,
                       const float* __restrict__ attd1, unsigned short* __restrict__ W1t) {
    int n = blockIdx.x;      // 0..143
    int k = threadIdx.x;     // 0..255
    float v;
    if (n < 128) {
        v = W1[(size_t)k * F1 + n];
    } else if (n < 136) {
        int h = n - 128; v = 0.f;
#pragma unroll
        for (int c = 0; c < 16; ++c) v += W1[(size_t)k * F1 + h * 16 + c] * atts1[h * 16 + c];
    } else {
        int h = n - 136; v = 0.f;
#pragma unroll
        for (int c = 0; c < 16; ++c) v += W1[(size_t)k * F1 + h * 16 + c] * attd1[h * 16 + c];
    }
    W1t[(size_t)n * NF + k] = f2bf(v);
}

// ---------- MFMA GEMM1: x[N,256] @ W1t144^T -> h1b[,128] bf16 + as1/ad1 ----------
// Full-K register preload: 16 outstanding dwordx4 loads per lane, then 8 MFMA steps.
__global__ __launch_bounds__(256) void gemm1m(const float* __restrict__ x,
                                              const unsigned short* __restrict__ W1t,
                                              unsigned short* __restrict__ h1b,
                                              float* __restrict__ as1,
                                              float* __restrict__ ad1) {
    int t = threadIdx.x;
    int wave = t >> 6, lane = t & 63;
    int mbase = blockIdx.x * 64 + wave * 16;
    int row = mbase + (lane & 15);
    int rowc = min(row, NODES - 1);
    int kg = lane >> 4;              // 0..3
    const float4* xr = (const float4*)(x + (size_t)rowc * NF + kg * 8);

    // preload entire K strip: lane covers k in {kg*8 + ks*32 .. +8}, ks=0..7
    float4 xa[16];
#pragma unroll
    for (int ks = 0; ks < 8; ++ks) {
        xa[2 * ks]     = xr[ks * 8];
        xa[2 * ks + 1] = xr[ks * 8 + 1];
    }

    f32x4 acc[9];
#pragma unroll
    for (int f = 0; f < 9; ++f) acc[f] = (f32x4){0.f, 0.f, 0.f, 0.f};

    const unsigned short* wb = W1t + (size_t)(lane & 15) * NF + kg * 8;

#pragma unroll
    for (int ks = 0; ks < 8; ++ks) {
        union { uint4 u; bf16x8 v; } A;
        float4 a0 = xa[2 * ks], a1 = xa[2 * ks + 1];
        A.u.x = pk2(a0.x, a0.y); A.u.y = pk2(a0.z, a0.w);
        A.u.z = pk2(a1.x, a1.y); A.u.w = pk2(a1.z, a1.w);
        const unsigned short* wk = wb + ks * 32;
#pragma unroll
        for (int f = 0; f < 9; ++f) {
            union { uint4 u; bf16x8 v; } B;
            B.u = *(const uint4*)(wk + (size_t)f * 16 * NF);
            acc[f] = __builtin_amdgcn_mfma_f32_16x16x32_bf16(A.v, B.v, acc[f], 0, 0, 0);
        }
    }

    // store: C/D layout col=lane&15, row=(lane>>4)*4+reg
    int col = lane & 15;
    int rbase = mbase + (lane >> 4) * 4;
#pragma unroll
    for (int f = 0; f < 8; ++f) {
#pragma unroll
        for (int i = 0; i < 4; ++i) {
            int r = rbase + i;
            if (r < NODES) h1b[(size_t)r * F1 + f * 16 + col] = f2bf(acc[f][i]);
        }
    }
#pragma unroll
    for (int i = 0; i < 4; ++i) {
        int r = rbase + i;
        if (r < NODES) {
            float v = acc[8][i];
            if (col < 8) as1[(size_t)r * NHEAD + col] = v;
            else ad1[(size_t)r * NHEAD + (col - 8)] = v;
        }
    }
}

// no-max softmax step: 8 channels per lane
#define PROC8(AV, HV)                                    \
    {                                                    \
        float l = (AV) + adv;                            \
        l = l > 0.f ? l : 0.2f * l;                      \
        float p = __expf(l);                             \
        den += p;                                        \
        acc[0] += p * bflo(HV.x); acc[1] += p * bfhi(HV.x); \
        acc[2] += p * bflo(HV.y); acc[3] += p * bfhi(HV.y); \
        acc[4] += p * bflo(HV.z); acc[5] += p * bfhi(HV.z); \
        acc[6] += p * bflo(HV.w); acc[7] += p * bfhi(HV.w); \
    }

// ---------- L1 gather: wave per dst, 4 edges/step, 8ch/lane, bias+ELU -> bf16 ----------
__global__ __launch_bounds__(256) void msg1(const int* __restrict__ rowPtr,
                                            const int* __restrict__ csrSrc,
                                            const float* __restrict__ as1,
                                            const float* __restrict__ ad1,
                                            const unsigned short* __restrict__ h1b,
                                            const float* __restrict__ b1,
                                            unsigned short* __restrict__ out1b) {
    int t = threadIdx.x;
    int wid = t >> 6, lane = t & 63;
    int d = blockIdx.x * 4 + wid;        // grid exact (50000/4)
    int g = lane >> 4;                    // edge subgroup 0..3
    int cl = lane & 15;                   // channel lane: ch 8*cl..8*cl+7
    int h = cl >> 1;                      // head
    float adv = ad1[(size_t)d * NHEAD + h];
    int rs = rowPtr[d], re = rowPtr[d + 1];
    float den = 0.f;
    float acc[8];
#pragma unroll
    for (int k = 0; k < 8; ++k) acc[k] = 0.f;

#define LD1(J0, AV, HV)                                               \
    {                                                                 \
        int j = (J0) + g;                                             \
        bool val = j < re;                                            \
        int jj = val ? j : re - 1;                                    \
        int ss = csrSrc[jj];                                          \
        AV = val ? as1[(size_t)ss * NHEAD + h] : -1e30f;              \
        HV = *(const uint4*)(h1b + (size_t)ss * F1 + cl * 8);         \
    }

    float av0, av1; uint4 hv0, hv1;
    LD1(rs, av0, hv0);
    LD1(rs + 4, av1, hv1);
    for (int j0 = rs; j0 < re; j0 += 8) {
        float ta, tb; uint4 ha, hb;
        LD1(j0 + 8, ta, ha);
        LD1(j0 + 12, tb, hb);
        PROC8(av0, hv0);
        PROC8(av1, hv1);
        av0 = ta; hv0 = ha; av1 = tb; hv1 = hb;
    }
#undef LD1

    // reduce across the 4 edge-groups
#pragma unroll
    for (int k = 0; k < 8; ++k) {
        acc[k] += __shfl_xor(acc[k], 16, 64);
        acc[k] += __shfl_xor(acc[k], 32, 64);
    }
    den += __shfl_xor(den, 16, 64);
    den += __shfl_xor(den, 32, 64);
    float invd = 1.f / (den + 1e-16f);

    if (g == 0) {
        const float4* bp = (const float4*)(b1 + cl * 8);
        float4 ba = bp[0], bb = bp[1];
        float v[8];
        v[0] = acc[0] * invd + ba.x; v[1] = acc[1] * invd + ba.y;
        v[2] = acc[2] * invd + ba.z; v[3] = acc[3] * invd + ba.w;
        v[4] = acc[4] * invd + bb.x; v[5] = acc[5] * invd + bb.y;
        v[6] = acc[6] * invd + bb.z; v[7] = acc[7] * invd + bb.w;
#pragma unroll
        for (int k = 0; k < 8; ++k) v[k] = v[k] > 0.f ? v[k] : expm1f(v[k]);
        uint4 o;
        o.x = pk2(v[0], v[1]); o.y = pk2(v[2], v[3]);
        o.z = pk2(v[4], v[5]); o.w = pk2(v[6], v[7]);
        *(uint4*)(out1b + (size_t)d * F1 + cl * 8) = o;
    }
}

// ---------- GEMM2: out1b[N,128]bf16 @ W2[128,40] -> h2b (bf16) + fused a2k ----------
__global__ __launch_bounds__(320) void gemm2k(const unsigned short* __restrict__ a,
                                              const float* __restrict__ W,
                                              const float* __restrict__ atts2,
                                              const float* __restrict__ attd2,
                                              unsigned short* __restrict__ h2b,
                                              float* __restrict__ as2,
                                              float* __restrict__ ad2) {
    __shared__ float xs[8][132];
    __shared__ float red[2][320];
    int t = threadIdx.x;
    int base = blockIdx.x * 8;           // grid exact (50000/8)
    if (t < 256) {
        int row = t >> 5, q = t & 31;
        uint2 u = *(const uint2*)(a + (size_t)(base + row) * F1 + q * 4);
        float4 f;
        f.x = bflo(u.x); f.y = bfhi(u.x); f.z = bflo(u.y); f.w = bfhi(u.y);
        *(float4*)(&xs[row][q * 4]) = f;
    }
    __syncthreads();
    int n = t / 40, c = t % 40;
    float acc = 0.f;
    for (int k4 = 0; k4 < 32; ++k4) {
        float4 xv = *(const float4*)(&xs[n][k4 * 4]);
        const float* wp = W + (size_t)k4 * 4 * NC + c;
        acc += xv.x * wp[0];
        acc += xv.y * wp[NC];
        acc += xv.z * wp[2 * NC];
        acc += xv.w * wp[3 * NC];
    }
    int node = base + n;
    h2b[(size_t)node * NC + c] = f2bf(acc);
    red[0][n * 40 + c] = acc * atts2[c];
    red[1][n * 40 + c] = acc * attd2[c];
    __syncthreads();
    if (t < 16) {
        int which = t >> 3, nn = t & 7;
        const float* p = red[which] + nn * 40;
        float s = 0.f;
        for (int q = 0; q < 40; ++q) s += p[q];
        if (which) ad2[base + nn] = s; else as2[base + nn] = s;
    }
}

// ---------- L2 gather: wave per dst, 8 edges/step, bias + log_softmax ----------
__global__ __launch_bounds__(256) void msg2(const int* __restrict__ rowPtr,
                                            const int* __restrict__ csrSrc,
                                            const float* __restrict__ as2,
                                            const float* __restrict__ ad2,
                                            const unsigned short* __restrict__ h2b,
                                            const float* __restrict__ b2,
                                            float* __restrict__ out) {
    int t = threadIdx.x;
    int wid = t >> 6, lane = t & 63;
    int d = blockIdx.x * 4 + wid;        // grid exact
    int g = lane >> 3;                    // edge subgroup 0..7
    int cl = lane & 7;                    // channel lane; active cl<5 (8 ch each)
    int clc = cl < 5 ? cl : 4;
    bool act = cl < 5;
    float adv = ad2[d];
    int rs = rowPtr[d], re = rowPtr[d + 1];
    float den = 0.f;
    float acc[8];
#pragma unroll
    for (int k = 0; k < 8; ++k) acc[k] = 0.f;

#define LD2(J0, AV, HV)                                               \
    {                                                                 \
        int j = (J0) + g;                                             \
        bool val = j < re;                                            \
        int jj = val ? j : re - 1;                                    \
        int ss = csrSrc[jj];                                          \
        AV = val ? as2[ss] : -1e30f;                                  \
        HV = *(const uint4*)(h2b + (size_t)ss * NC + clc * 8);        \
    }

    float av0, av1; uint4 hv0, hv1;
    LD2(rs, av0, hv0);
    LD2(rs + 8, av1, hv1);
    for (int j0 = rs; j0 < re; j0 += 16) {
        float ta, tb; uint4 ha, hb;
        LD2(j0 + 16, ta, ha);
        LD2(j0 + 24, tb, hb);
        PROC8(av0, hv0);
        PROC8(av1, hv1);
        av0 = ta; hv0 = ha; av1 = tb; hv1 = hb;
    }
#undef LD2

    // reduce across the 8 edge-groups
#pragma unroll
    for (int k = 0; k < 8; ++k) {
        acc[k] += __shfl_xor(acc[k], 8, 64);
        acc[k] += __shfl_xor(acc[k], 16, 64);
        acc[k] += __shfl_xor(acc[k], 32, 64);
    }
    den += __shfl_xor(den, 8, 64);
    den += __shfl_xor(den, 16, 64);
    den += __shfl_xor(den, 32, 64);
    float invd = 1.f / (den + 1e-16f);

    float v[8];
    float mk = -1e30f;
    if (act) {
        const float4* bp = (const float4*)(b2 + cl * 8);
        float4 ba = bp[0], bb = bp[1];
        v[0] = acc[0] * invd + ba.x; v[1] = acc[1] * invd + ba.y;
        v[2] = acc[2] * invd + ba.z; v[3] = acc[3] * invd + ba.w;
        v[4] = acc[4] * invd + bb.x; v[5] = acc[5] * invd + bb.y;
        v[6] = acc[6] * invd + bb.z; v[7] = acc[7] * invd + bb.w;
#pragma unroll
        for (int k = 0; k < 8; ++k) mk = fmaxf(mk, v[k]);
    }
    mk = fmaxf(mk, __shfl_xor(mk, 1, 64));
    mk = fmaxf(mk, __shfl_xor(mk, 2, 64));
    mk = fmaxf(mk, __shfl_xor(mk, 4, 64));
    float e = 0.f;
    if (act) {
#pragma unroll
        for (int k = 0; k < 8; ++k) e += __expf(v[k] - mk);
    }
    e += __shfl_xor(e, 1, 64);
    e += __shfl_xor(e, 2, 64);
    e += __shfl_xor(e, 4, 64);
    float lse = mk + logf(e);
    if (lane < 5) {   // group 0, active channel lanes
        float4 o0 = make_float4(v[0] - lse, v[1] - lse, v[2] - lse, v[3] - lse);
        float4 o1 = make_float4(v[4] - lse, v[5] - lse, v[6] - lse, v[7] - lse);
        float* po = out + (size_t)d * NC + cl * 8;
        *(float4*)po = o0;
        *(float4*)(po + 4) = o1;
    }
}

extern "C" void kernel_launch(void* const* d_in, const int* in_sizes, int n_in,
                              void* d_out, int out_size, void* d_ws, size_t ws_size,
                              hipStream_t stream) {
    const float* x       = (const float*)d_in[0];
    const unsigned* eidx = (const unsigned*)d_in[1];
    const float* W1      = (const float*)d_in[2];
    const float* atts1   = (const float*)d_in[3];
    const float* attd1   = (const float*)d_in[4];
    const float* b1      = (const float*)d_in[5];
    const float* W2      = (const float*)d_in[6];
    const float* atts2   = (const float*)d_in[7];
    const float* attd2   = (const float*)d_in[8];
    const float* b2      = (const float*)d_in[9];
    float* out = (float*)d_out;

    char* base = (char*)d_ws;
    size_t off = 0;
    auto takeB = [&](size_t bytes) {
        void* p = base + off;
        off = (off + bytes + 255) & ~(size_t)255;
        return p;
    };
    unsigned* flag = (unsigned*)takeB(256);
    int* cnt       = (int*)takeB((size_t)NODES * 4);
    int* fill      = (int*)takeB((size_t)NODES * 4);
    int* rowPtr    = (int*)takeB((size_t)(NODES + 1) * 4);
    int* blockSum  = (int*)takeB(SCAN_BLK * 4);
    int* blockOff  = (int*)takeB(SCAN_BLK * 4);
    int* csrSrc    = (int*)takeB((size_t)ETOT * 4 + 256);
    unsigned short* W1t  = (unsigned short*)takeB((size_t)144 * NF * 2);
    unsigned short* h1b  = (unsigned short*)takeB((size_t)NODES * F1 * 2);
    float* as1     = (float*)takeB((size_t)NODES * NHEAD * 4);
    float* ad1     = (float*)takeB((size_t)NODES * NHEAD * 4);
    unsigned short* out1b = (unsigned short*)takeB((size_t)NODES * F1 * 2);
    unsigned short* h2b  = (unsigned short*)takeB((size_t)NODES * NC * 2 + 256);
    float* as2     = (float*)takeB((size_t)NODES * 4);
    float* ad2     = (float*)takeB((size_t)NODES * 4);

    hipMemsetAsync(flag, 0, 4, stream);
    hipMemsetAsync(cnt, 0, (size_t)NODES * 4, stream);
    hipMemsetAsync(fill, 0, (size_t)NODES * 4, stream);

    detect_k<<<1, 256, 0, stream>>>(eidx, flag);

    // CSR build (by destination), reading edge_index directly
    hist_k<<<(ETOT + 255) / 256, 256, 0, stream>>>(eidx, flag, cnt);
    scanA<<<SCAN_BLK, 256, 0, stream>>>(cnt, rowPtr, blockSum);
    scanB<<<1, 256, 0, stream>>>(blockSum, blockOff);
    scanC<<<SCAN_BLK, 256, 0, stream>>>(rowPtr, blockOff);
    scatter_k<<<(ETOT + 255) / 256, 256, 0, stream>>>(eidx, flag, rowPtr, fill, csrSrc);

    // Layer 1 (MFMA GEMM with fused a1k columns)
    prepW1<<<144, 256, 0, stream>>>(W1, atts1, attd1, W1t);
    gemm1m<<<(NODES + 63) / 64, 256, 0, stream>>>(x, W1t, h1b, as1, ad1);
    msg1<<<NODES / 4, 256, 0, stream>>>(rowPtr, csrSrc, as1, ad1, h1b, b1, out1b);

    // Layer 2
    gemm2k<<<NODES / 8, 320, 0, stream>>>(out1b, W2, atts2, attd2, h2b, as2, ad2);
    msg2<<<NODES / 4, 256, 0, stream>>>(rowPtr, csrSrc, as2, ad2, h2b, b2, out);
}

// Round 9
// 239.071 us; speedup vs baseline: 5.9127x; 1.0803x over previous
//
#include <hip/hip_runtime.h>
#include <math.h>

#define NODES 50000
#define NEDGE 800000
#define ETOT  (NEDGE + NODES)   // edges + self loops = 850000
#define NF    256
#define F1    128               // HEADS*NHID
#define NHEAD 8
#define NHID  16
#define NC    40
#define SCAN_BLK 196            // ceil((NODES+1)/256)

typedef __attribute__((ext_vector_type(8))) short bf16x8;
typedef __attribute__((ext_vector_type(4))) float f32x4;

__device__ __forceinline__ float bflo(unsigned u) { return __uint_as_float(u << 16); }
__device__ __forceinline__ float bfhi(unsigned u) { return __uint_as_float(u & 0xffff0000u); }
__device__ __forceinline__ unsigned short f2bf(float f) {
    unsigned u = __float_as_uint(f);
    unsigned r = u + 0x7fffu + ((u >> 16) & 1u);   // RNE
    return (unsigned short)(r >> 16);
}
__device__ __forceinline__ unsigned pk2(float a, float b) {
    return (unsigned)f2bf(a) | ((unsigned)f2bf(b) << 16);
}

// ---------- edge index dtype detect ----------
__global__ void detect_k(const unsigned* __restrict__ u, unsigned* __restrict__ flag) {
    int t = threadIdx.x;              // 256 threads
    if (u[2 * t + 1] != 0u) atomicOr(flag, 1u);   // nonzero hi-word pattern => int32 data
}

// ---------- CSR build (reads edge_index directly) ----------
__global__ void hist_k(const unsigned* __restrict__ u, const unsigned* __restrict__ flag,
                       int* __restrict__ cnt) {
    int e = blockIdx.x * 256 + threadIdx.x;
    if (e >= ETOT) return;
    int d;
    if (e < NEDGE) d = (*flag) ? (int)u[NEDGE + e] : (int)u[2 * NEDGE + 2 * e];
    else d = e - NEDGE;
    atomicAdd(&cnt[d], 1);
}

// ---------- multi-block exclusive scan of cnt[0..NODES] -> rowPtr ----------
__global__ __launch_bounds__(256) void scanA(const int* __restrict__ cnt,
                                             int* __restrict__ rowPtr,
                                             int* __restrict__ blockSum) {
    int idx = blockIdx.x * 256 + threadIdx.x;
    int lane = threadIdx.x & 63, w = threadIdx.x >> 6;
    int v = (idx < NODES) ? cnt[idx] : 0;
    int s = v;
#pragma unroll
    for (int off = 1; off < 64; off <<= 1) {
        int o = __shfl_up(s, off, 64);
        if (lane >= off) s += o;
    }
    __shared__ int wsum[4];
    if (lane == 63) wsum[w] = s;
    __syncthreads();
    int wadd = 0;
    for (int i = 0; i < w; ++i) wadd += wsum[i];
    int incl = s + wadd;
    if (idx <= NODES) rowPtr[idx] = incl - v;        // block-local exclusive
    if (threadIdx.x == 255) blockSum[blockIdx.x] = incl;
}

__global__ __launch_bounds__(256) void scanB(const int* __restrict__ blockSum,
                                             int* __restrict__ blockOff) {
    __shared__ int sh[256];
    int t = threadIdx.x;
    int v = (t < SCAN_BLK) ? blockSum[t] : 0;
    sh[t] = v;
    __syncthreads();
    for (int off = 1; off < 256; off <<= 1) {
        int o = (t >= off) ? sh[t - off] : 0;
        __syncthreads();
        sh[t] += o;
        __syncthreads();
    }
    if (t < SCAN_BLK) blockOff[t] = sh[t] - v;       // exclusive
}

__global__ __launch_bounds__(256) void scanC(int* __restrict__ rowPtr,
                                             const int* __restrict__ blockOff) {
    int idx = blockIdx.x * 256 + threadIdx.x;
    if (idx <= NODES) rowPtr[idx] += blockOff[blockIdx.x];
}

__global__ void scatter_k(const unsigned* __restrict__ u, const unsigned* __restrict__ flag,
                          const int* __restrict__ rowPtr, int* __restrict__ fill,
                          int* __restrict__ csrSrc) {
    int e = blockIdx.x * 256 + threadIdx.x;
    if (e >= ETOT) return;
    int s, d;
    if (e < NEDGE) {
        if (*flag) { s = (int)u[e]; d = (int)u[NEDGE + e]; }
        else       { s = (int)u[2 * e]; d = (int)u[2 * NEDGE + 2 * e]; }
    } else s = d = e - NEDGE;
    int pos = rowPtr[d] + atomicAdd(&fill[d], 1);
    csrSrc[pos] = s;
}

// ---------- prep: W1t144[144][256] bf16 = [W1^T ; W1.atts1 per head ; W1.attd1] ----------
__global__ void prepW1(const float* __restrict__ W1, const float* __restrict__ atts1,
                       const float* __restrict__ attd1, unsigned short* __restrict__ W1t) {
    int n = blockIdx.x;      // 0..143
    int k = threadIdx.x;     // 0..255
    float v;
    if (n < 128) {
        v = W1[(size_t)k * F1 + n];
    } else if (n < 136) {
        int h = n - 128; v = 0.f;
#pragma unroll
        for (int c = 0; c < 16; ++c) v += W1[(size_t)k * F1 + h * 16 + c] * atts1[h * 16 + c];
    } else {
        int h = n - 136; v = 0.f;
#pragma unroll
        for (int c = 0; c < 16; ++c) v += W1[(size_t)k * F1 + h * 16 + c] * attd1[h * 16 + c];
    }
    W1t[(size_t)n * NF + k] = f2bf(v);
}

// ---------- MFMA GEMM1: x[N,256] @ W1t144^T -> h1b[,128] bf16 + as1/ad1 ----------
// x loads issued up-front behind a sched_barrier (16-deep MLP), W1t staged in
// LDS (XOR-swizzled) so B-fragments come from ds_read_b128, not global.
__global__ __launch_bounds__(256) void gemm1m(const float* __restrict__ x,
                                              const unsigned short* __restrict__ W1t,
                                              unsigned short* __restrict__ h1b,
                                              float* __restrict__ as1,
                                              float* __restrict__ ad1) {
    __shared__ uint4 wlds[4608];         // 144 rows x 32 uint4 = 73728 B
    int t = threadIdx.x;
    int wave = t >> 6, lane = t & 63;
    int mbase = blockIdx.x * 64 + wave * 16;
    int row = mbase + (lane & 15);
    int rowc = min(row, NODES - 1);
    int kg = lane >> 4;              // 0..3
    const float4* xr = (const float4*)(x + (size_t)rowc * NF + kg * 8);

    // 1) issue the full K-strip loads (16 independent dwordx4 in flight)
    float4 xa[16];
#pragma unroll
    for (int ks = 0; ks < 8; ++ks) {
        xa[2 * ks]     = xr[ks * 8];
        xa[2 * ks + 1] = xr[ks * 8 + 1];
    }
    __builtin_amdgcn_sched_barrier(0);   // pin loads before the staging code

    // 2) stage W1t into LDS, swizzled: uint4 idx i -> i ^ (row&7), row = i>>5
#pragma unroll
    for (int it = 0; it < 18; ++it) {
        int i = it * 256 + t;
        wlds[i ^ ((i >> 5) & 7)] = ((const uint4*)W1t)[i];
    }
    __syncthreads();                     // also drains the x loads (all parallel)

    f32x4 acc[9];
#pragma unroll
    for (int f = 0; f < 9; ++f) acc[f] = (f32x4){0.f, 0.f, 0.f, 0.f};

    int r = lane & 15;
    int swz = r & 7;
    int rb = r * 32 + kg;                // uint4 index base within a frag row-block

#pragma unroll
    for (int ks = 0; ks < 8; ++ks) {
        union { uint4 u; bf16x8 v; } A;
        float4 a0 = xa[2 * ks], a1 = xa[2 * ks + 1];
        A.u.x = pk2(a0.x, a0.y); A.u.y = pk2(a0.z, a0.w);
        A.u.z = pk2(a1.x, a1.y); A.u.w = pk2(a1.z, a1.w);
#pragma unroll
        for (int f = 0; f < 9; ++f) {
            union { uint4 u; bf16x8 v; } B;
            B.u = wlds[(f * 512 + rb + ks * 4) ^ swz];
            acc[f] = __builtin_amdgcn_mfma_f32_16x16x32_bf16(A.v, B.v, acc[f], 0, 0, 0);
        }
    }

    // store: C/D layout col=lane&15, row=(lane>>4)*4+reg
    int col = lane & 15;
    int rbase = mbase + (lane >> 4) * 4;
#pragma unroll
    for (int f = 0; f < 8; ++f) {
#pragma unroll
        for (int i = 0; i < 4; ++i) {
            int rr = rbase + i;
            if (rr < NODES) h1b[(size_t)rr * F1 + f * 16 + col] = f2bf(acc[f][i]);
        }
    }
#pragma unroll
    for (int i = 0; i < 4; ++i) {
        int rr = rbase + i;
        if (rr < NODES) {
            float v = acc[8][i];
            if (col < 8) as1[(size_t)rr * NHEAD + col] = v;
            else ad1[(size_t)rr * NHEAD + (col - 8)] = v;
        }
    }
}

// no-max softmax step: 8 channels per lane
#define PROC8(AV, HV)                                    \
    {                                                    \
        float l = (AV) + adv;                            \
        l = l > 0.f ? l : 0.2f * l;                      \
        float p = __expf(l);                             \
        den += p;                                        \
        acc[0] += p * bflo(HV.x); acc[1] += p * bfhi(HV.x); \
        acc[2] += p * bflo(HV.y); acc[3] += p * bfhi(HV.y); \
        acc[4] += p * bflo(HV.z); acc[5] += p * bfhi(HV.z); \
        acc[6] += p * bflo(HV.w); acc[7] += p * bfhi(HV.w); \
    }

// ---------- L1 gather: wave per dst, 4 edges/step, 8ch/lane, bias+ELU -> bf16 ----------
__global__ __launch_bounds__(256) void msg1(const int* __restrict__ rowPtr,
                                            const int* __restrict__ csrSrc,
                                            const float* __restrict__ as1,
                                            const float* __restrict__ ad1,
                                            const unsigned short* __restrict__ h1b,
                                            const float* __restrict__ b1,
                                            unsigned short* __restrict__ out1b) {
    int t = threadIdx.x;
    int wid = t >> 6, lane = t & 63;
    int d = blockIdx.x * 4 + wid;        // grid exact (50000/4)
    int g = lane >> 4;                    // edge subgroup 0..3
    int cl = lane & 15;                   // channel lane: ch 8*cl..8*cl+7
    int h = cl >> 1;                      // head
    float adv = ad1[(size_t)d * NHEAD + h];
    int rs = rowPtr[d], re = rowPtr[d + 1];
    float den = 0.f;
    float acc[8];
#pragma unroll
    for (int k = 0; k < 8; ++k) acc[k] = 0.f;

    const char* as1c = (const char*)as1;
    const char* h1c = (const char*)h1b;
    unsigned hoff = (unsigned)(h << 2);
    unsigned coff = (unsigned)(cl << 4);

#define LD1(J0, AV, HV)                                               \
    {                                                                 \
        int j = (J0) + g;                                             \
        bool val = j < re;                                            \
        int jj = val ? j : re - 1;                                    \
        unsigned ss = (unsigned)csrSrc[jj];                           \
        AV = val ? *(const float*)(as1c + (ss << 5) + hoff) : -1e30f; \
        HV = *(const uint4*)(h1c + (ss << 8) + coff);                 \
    }

    float av0, av1; uint4 hv0, hv1;
    LD1(rs, av0, hv0);
    LD1(rs + 4, av1, hv1);
    for (int j0 = rs; j0 < re; j0 += 8) {
        float ta, tb; uint4 ha, hb;
        LD1(j0 + 8, ta, ha);
        LD1(j0 + 12, tb, hb);
        PROC8(av0, hv0);
        PROC8(av1, hv1);
        av0 = ta; hv0 = ha; av1 = tb; hv1 = hb;
    }
#undef LD1

    // reduce across the 4 edge-groups
#pragma unroll
    for (int k = 0; k < 8; ++k) {
        acc[k] += __shfl_xor(acc[k], 16, 64);
        acc[k] += __shfl_xor(acc[k], 32, 64);
    }
    den += __shfl_xor(den, 16, 64);
    den += __shfl_xor(den, 32, 64);
    float invd = 1.f / (den + 1e-16f);

    if (g == 0) {
        const float4* bp = (const float4*)(b1 + cl * 8);
        float4 ba = bp[0], bb = bp[1];
        float v[8];
        v[0] = acc[0] * invd + ba.x; v[1] = acc[1] * invd + ba.y;
        v[2] = acc[2] * invd + ba.z; v[3] = acc[3] * invd + ba.w;
        v[4] = acc[4] * invd + bb.x; v[5] = acc[5] * invd + bb.y;
        v[6] = acc[6] * invd + bb.z; v[7] = acc[7] * invd + bb.w;
#pragma unroll
        for (int k = 0; k < 8; ++k) {
            float ev = __expf(v[k]) - 1.f;          // ELU negative branch
            v[k] = v[k] > 0.f ? v[k] : ev;
        }
        uint4 o;
        o.x = pk2(v[0], v[1]); o.y = pk2(v[2], v[3]);
        o.z = pk2(v[4], v[5]); o.w = pk2(v[6], v[7]);
        *(uint4*)(out1b + (size_t)d * F1 + cl * 8) = o;
    }
}

// ---------- GEMM2: out1b[N,128]bf16 @ W2[128,40] -> h2b (bf16) + fused a2k ----------
__global__ __launch_bounds__(320) void gemm2k(const unsigned short* __restrict__ a,
                                              const float* __restrict__ W,
                                              const float* __restrict__ atts2,
                                              const float* __restrict__ attd2,
                                              unsigned short* __restrict__ h2b,
                                              float* __restrict__ as2,
                                              float* __restrict__ ad2) {
    __shared__ float xs[8][132];
    __shared__ float red[2][320];
    int t = threadIdx.x;
    int base = blockIdx.x * 8;           // grid exact (50000/8)
    if (t < 256) {
        int row = t >> 5, q = t & 31;
        uint2 u = *(const uint2*)(a + (size_t)(base + row) * F1 + q * 4);
        float4 f;
        f.x = bflo(u.x); f.y = bfhi(u.x); f.z = bflo(u.y); f.w = bfhi(u.y);
        *(float4*)(&xs[row][q * 4]) = f;
    }
    __syncthreads();
    int n = t / 40, c = t % 40;
    float acc = 0.f;
    for (int k4 = 0; k4 < 32; ++k4) {
        float4 xv = *(const float4*)(&xs[n][k4 * 4]);
        const float* wp = W + (size_t)k4 * 4 * NC + c;
        acc += xv.x * wp[0];
        acc += xv.y * wp[NC];
        acc += xv.z * wp[2 * NC];
        acc += xv.w * wp[3 * NC];
    }
    int node = base + n;
    h2b[(size_t)node * NC + c] = f2bf(acc);
    red[0][n * 40 + c] = acc * atts2[c];
    red[1][n * 40 + c] = acc * attd2[c];
    __syncthreads();
    if (t < 16) {
        int which = t >> 3, nn = t & 7;
        const float* p = red[which] + nn * 40;
        float s = 0.f;
        for (int q = 0; q < 40; ++q) s += p[q];
        if (which) ad2[base + nn] = s; else as2[base + nn] = s;
    }
}

// ---------- L2 gather: wave per dst, 8 edges/step, bias + log_softmax ----------
__global__ __launch_bounds__(256) void msg2(const int* __restrict__ rowPtr,
                                            const int* __restrict__ csrSrc,
                                            const float* __restrict__ as2,
                                            const float* __restrict__ ad2,
                                            const unsigned short* __restrict__ h2b,
                                            const float* __restrict__ b2,
                                            float* __restrict__ out) {
    int t = threadIdx.x;
    int wid = t >> 6, lane = t & 63;
    int d = blockIdx.x * 4 + wid;        // grid exact
    int g = lane >> 3;                    // edge subgroup 0..7
    int cl = lane & 7;                    // channel lane; active cl<5 (8 ch each)
    int clc = cl < 5 ? cl : 4;
    bool act = cl < 5;
    float adv = ad2[d];
    int rs = rowPtr[d], re = rowPtr[d + 1];
    float den = 0.f;
    float acc[8];
#pragma unroll
    for (int k = 0; k < 8; ++k) acc[k] = 0.f;

    const char* as2c = (const char*)as2;
    const char* h2c = (const char*)h2b;
    unsigned coff = (unsigned)(clc << 4);

#define LD2(J0, AV, HV)                                               \
    {                                                                 \
        int j = (J0) + g;                                             \
        bool val = j < re;                                            \
        int jj = val ? j : re - 1;                                    \
        unsigned ss = (unsigned)csrSrc[jj];                           \
        AV = val ? *(const float*)(as2c + (ss << 2)) : -1e30f;        \
        HV = *(const uint4*)(h2c + ss * 80u + coff);                  \
    }

    float av0, av1; uint4 hv0, hv1;
    LD2(rs, av0, hv0);
    LD2(rs + 8, av1, hv1);
    for (int j0 = rs; j0 < re; j0 += 16) {
        float ta, tb; uint4 ha, hb;
        LD2(j0 + 16, ta, ha);
        LD2(j0 + 24, tb, hb);
        PROC8(av0, hv0);
        PROC8(av1, hv1);
        av0 = ta; hv0 = ha; av1 = tb; hv1 = hb;
    }
#undef LD2

    // reduce across the 8 edge-groups
#pragma unroll
    for (int k = 0; k < 8; ++k) {
        acc[k] += __shfl_xor(acc[k], 8, 64);
        acc[k] += __shfl_xor(acc[k], 16, 64);
        acc[k] += __shfl_xor(acc[k], 32, 64);
    }
    den += __shfl_xor(den, 8, 64);
    den += __shfl_xor(den, 16, 64);
    den += __shfl_xor(den, 32, 64);
    float invd = 1.f / (den + 1e-16f);

    float v[8];
    float mk = -1e30f;
    if (act) {
        const float4* bp = (const float4*)(b2 + cl * 8);
        float4 ba = bp[0], bb = bp[1];
        v[0] = acc[0] * invd + ba.x; v[1] = acc[1] * invd + ba.y;
        v[2] = acc[2] * invd + ba.z; v[3] = acc[3] * invd + ba.w;
        v[4] = acc[4] * invd + bb.x; v[5] = acc[5] * invd + bb.y;
        v[6] = acc[6] * invd + bb.z; v[7] = acc[7] * invd + bb.w;
#pragma unroll
        for (int k = 0; k < 8; ++k) mk = fmaxf(mk, v[k]);
    }
    mk = fmaxf(mk, __shfl_xor(mk, 1, 64));
    mk = fmaxf(mk, __shfl_xor(mk, 2, 64));
    mk = fmaxf(mk, __shfl_xor(mk, 4, 64));
    float e = 0.f;
    if (act) {
#pragma unroll
        for (int k = 0; k < 8; ++k) e += __expf(v[k] - mk);
    }
    e += __shfl_xor(e, 1, 64);
    e += __shfl_xor(e, 2, 64);
    e += __shfl_xor(e, 4, 64);
    float lse = mk + logf(e);
    if (lane < 5) {   // group 0, active channel lanes
        float4 o0 = make_float4(v[0] - lse, v[1] - lse, v[2] - lse, v[3] - lse);
        float4 o1 = make_float4(v[4] - lse, v[5] - lse, v[6] - lse, v[7] - lse);
        float* po = out + (size_t)d * NC + cl * 8;
        *(float4*)po = o0;
        *(float4*)(po + 4) = o1;
    }
}

extern "C" void kernel_launch(void* const* d_in, const int* in_sizes, int n_in,
                              void* d_out, int out_size, void* d_ws, size_t ws_size,
                              hipStream_t stream) {
    const float* x       = (const float*)d_in[0];
    const unsigned* eidx = (const unsigned*)d_in[1];
    const float* W1      = (const float*)d_in[2];
    const float* atts1   = (const float*)d_in[3];
    const float* attd1   = (const float*)d_in[4];
    const float* b1      = (const float*)d_in[5];
    const float* W2      = (const float*)d_in[6];
    const float* atts2   = (const float*)d_in[7];
    const float* attd2   = (const float*)d_in[8];
    const float* b2      = (const float*)d_in[9];
    float* out = (float*)d_out;

    char* base = (char*)d_ws;
    size_t off = 0;
    auto takeB = [&](size_t bytes) {
        void* p = base + off;
        off = (off + bytes + 255) & ~(size_t)255;
        return p;
    };
    unsigned* flag = (unsigned*)takeB(256);
    int* cnt       = (int*)takeB((size_t)NODES * 4);
    int* fill      = (int*)takeB((size_t)NODES * 4);
    int* rowPtr    = (int*)takeB((size_t)(NODES + 1) * 4);
    int* blockSum  = (int*)takeB(SCAN_BLK * 4);
    int* blockOff  = (int*)takeB(SCAN_BLK * 4);
    int* csrSrc    = (int*)takeB((size_t)ETOT * 4 + 256);
    unsigned short* W1t  = (unsigned short*)takeB((size_t)144 * NF * 2);
    unsigned short* h1b  = (unsigned short*)takeB((size_t)NODES * F1 * 2);
    float* as1     = (float*)takeB((size_t)NODES * NHEAD * 4);
    float* ad1     = (float*)takeB((size_t)NODES * NHEAD * 4);
    unsigned short* out1b = (unsigned short*)takeB((size_t)NODES * F1 * 2);
    unsigned short* h2b  = (unsigned short*)takeB((size_t)NODES * NC * 2 + 256);
    float* as2     = (float*)takeB((size_t)NODES * 4);
    float* ad2     = (float*)takeB((size_t)NODES * 4);

    hipMemsetAsync(flag, 0, 4, stream);
    hipMemsetAsync(cnt, 0, (size_t)NODES * 4, stream);
    hipMemsetAsync(fill, 0, (size_t)NODES * 4, stream);

    detect_k<<<1, 256, 0, stream>>>(eidx, flag);

    // CSR build (by destination), reading edge_index directly
    hist_k<<<(ETOT + 255) / 256, 256, 0, stream>>>(eidx, flag, cnt);
    scanA<<<SCAN_BLK, 256, 0, stream>>>(cnt, rowPtr, blockSum);
    scanB<<<1, 256, 0, stream>>>(blockSum, blockOff);
    scanC<<<SCAN_BLK, 256, 0, stream>>>(rowPtr, blockOff);
    scatter_k<<<(ETOT + 255) / 256, 256, 0, stream>>>(eidx, flag, rowPtr, fill, csrSrc);

    // Layer 1 (MFMA GEMM with fused a1k columns)
    prepW1<<<144, 256, 0, stream>>>(W1, atts1, attd1, W1t);
    gemm1m<<<(NODES + 63) / 64, 256, 0, stream>>>(x, W1t, h1b, as1, ad1);
    msg1<<<NODES / 4, 256, 0, stream>>>(rowPtr, csrSrc, as1, ad1, h1b, b1, out1b);

    // Layer 2
    gemm2k<<<NODES / 8, 320, 0, stream>>>(out1b, W2, atts2, attd2, h2b, as2, ad2);
    msg2<<<NODES / 4, 256, 0, stream>>>(rowPtr, csrSrc, as2, ad2, h2b, b2, out);
}